// Round 11
// baseline (2728.537 us; speedup 1.0000x reference)
//
#include <hip/hip_runtime.h>
#include <math.h>

#define D_IN 63
#define D_MODEL 256
#define N_CLS 14
#define NL 4
#define D_INNER 512
#define D_STATE 128
#define NH 8
#define HP 64
#define DCONV 4
#define CONV_CH 768
#define PROJ 1288
#define XBCDT 776
#define EPS 1e-5f
#define BSZ 32
#define LSEQ 1024
#define NTOK (BSZ*LSEQ)

#define SSEG 4
#define TSEG (LSEQ/SSEG)
#define CT 16
#define RS 8

// weight-pack region (ushort offsets)
#define S_IN   16384
#define S_IP   1318912
#define S_OP   524288
#define IN_HI  0
#define IN_LO  16384
#define IP_HI  32768
#define IP_LO  (32768 + S_IP)
#define OP_HI  (32768 + 2*S_IP)
#define OP_LO  (OP_HI + S_OP)
#define TOTPK  (S_IN + S_IP + S_OP)
#define WS_BASE ((size_t)NTOK * 1816)
#define WS_NEED ((WS_BASE + (size_t)TOTPK) * 4)

typedef __attribute__((ext_vector_type(8))) short bf16x8;
typedef __attribute__((ext_vector_type(4))) float f32x4;
typedef unsigned short u16;

__device__ __forceinline__ float silu_f(float x) { return x / (1.f + expf(-x)); }

__device__ __forceinline__ unsigned short f2bf(float x) {
    union { float f; unsigned u; } v; v.f = x;
    unsigned r = v.u + 0x7FFFu + ((v.u >> 16) & 1u);
    return (unsigned short)(r >> 16);
}
__device__ __forceinline__ float bf2f(unsigned short h) {
    union { float f; unsigned u; } v; v.u = ((unsigned)h) << 16; return v.f;
}
// trunc hi/lo split — identical decomposition to the old in-kernel GEMM split
__device__ __forceinline__ void split2(float v, u16& hi, u16& lo) {
    unsigned u = __float_as_uint(v);
    unsigned hb = u & 0xFFFF0000u;
    float r = v - __uint_as_float(hb);
    hi = (u16)(u >> 16);
    lo = (u16)(__float_as_uint(r) >> 16);
}

// swizzle for 8 groups of 16 values (proven 0-conflict)
__device__ __forceinline__ int swz8(int n) {
    int g = n >> 4, j = (n >> 2) & 3, e = n & 3;
    return (g << 4) + (((j + (g >> 1)) & 3) << 2) + e;
}

__device__ __forceinline__ float2 block_reduce2(float a, float b, float* sred) {
    #pragma unroll
    for (int off = 32; off >= 1; off >>= 1) {
        a += __shfl_xor(a, off);
        b += __shfl_xor(b, off);
    }
    int wid = threadIdx.x >> 6, lane = threadIdx.x & 63;
    if (lane == 0) { sred[wid * 2] = a; sred[wid * 2 + 1] = b; }
    __syncthreads();
    a = sred[0] + sred[2] + sred[4] + sred[6];
    b = sred[1] + sred[3] + sred[5] + sred[7];
    __syncthreads();
    return make_float2(a, b);
}

// ---------------- pack all weights to bf16 hi/lo planes ----------------
__global__ __launch_bounds__(256)
void k_pack_weights(const float* __restrict__ in_w, const float* __restrict__ inproj,
                    const float* __restrict__ outp, u16* __restrict__ WP) {
    int idx = blockIdx.x * 256 + threadIdx.x;
    float v; int hi_off, lo_off;
    if (idx < S_IN) {
        int n = idx >> 6, k = idx & 63;
        v = (k < D_IN) ? in_w[n * D_IN + k] : 0.f;
        hi_off = IN_HI + idx; lo_off = IN_LO + idx;
    } else if (idx < S_IN + S_IP) {
        int j = idx - S_IN;
        v = inproj[j];
        hi_off = IP_HI + j; lo_off = IP_LO + j;
    } else {
        int j = idx - S_IN - S_IP;
        v = outp[j];
        hi_off = OP_HI + j; lo_off = OP_LO + j;
    }
    unsigned short h = f2bf(v);
    unsigned short l = f2bf(v - bf2f(h));
    WP[hi_off] = h; WP[lo_off] = l;
}

// ---------------- MFMA GEMM, all operands pre-split bf16 hi/lo planes ----------
#define LDKP 40
__global__ __launch_bounds__(256, 2)
void k_gemm_bb(const u16* __restrict__ Ahg, const u16* __restrict__ Alg,
               const u16* __restrict__ Bhg, const u16* __restrict__ Blg,
               float* __restrict__ C, int M, int N, int K) {
    __shared__ u16 Ah[128][LDKP], Al[128][LDKP];
    __shared__ u16 Bh[128][LDKP], Bl[128][LDKP];
    int n0 = blockIdx.x * 128, m0 = blockIdx.y * 128;
    int tid = threadIdx.x;
    int srow = tid >> 1, sk = (tid & 1) * 16;
    int lane = tid & 63, wave = tid >> 6;
    int wm = (wave >> 1) * 64, wn = (wave & 1) * 64;
    int ln = lane & 15, quad = lane >> 4;
    f32x4 acc[4][4];
    #pragma unroll
    for (int i = 0; i < 4; i++)
        #pragma unroll
        for (int j = 0; j < 4; j++) acc[i][j] = (f32x4){0.f, 0.f, 0.f, 0.f};
    const u16* Ahp = Ahg + (size_t)(m0 + srow) * K + sk;
    const u16* Alp = Alg + (size_t)(m0 + srow) * K + sk;
    const u16* Bhp = Bhg + (size_t)(n0 + srow) * K + sk;
    const u16* Blp = Blg + (size_t)(n0 + srow) * K + sk;
    bool bval = (n0 + srow) < N;
    uint4 z4 = make_uint4(0u, 0u, 0u, 0u);
    for (int k0 = 0; k0 < K; k0 += 32) {
        uint4 ah0 = *(const uint4*)(Ahp + k0);
        uint4 ah1 = *(const uint4*)(Ahp + k0 + 8);
        uint4 al0 = *(const uint4*)(Alp + k0);
        uint4 al1 = *(const uint4*)(Alp + k0 + 8);
        uint4 bh0 = bval ? *(const uint4*)(Bhp + k0) : z4;
        uint4 bh1 = bval ? *(const uint4*)(Bhp + k0 + 8) : z4;
        uint4 bl0 = bval ? *(const uint4*)(Blp + k0) : z4;
        uint4 bl1 = bval ? *(const uint4*)(Blp + k0 + 8) : z4;
        __syncthreads();
        *(uint4*)&Ah[srow][sk]     = ah0;
        *(uint4*)&Ah[srow][sk + 8] = ah1;
        *(uint4*)&Al[srow][sk]     = al0;
        *(uint4*)&Al[srow][sk + 8] = al1;
        *(uint4*)&Bh[srow][sk]     = bh0;
        *(uint4*)&Bh[srow][sk + 8] = bh1;
        *(uint4*)&Bl[srow][sk]     = bl0;
        *(uint4*)&Bl[srow][sk + 8] = bl1;
        __syncthreads();
        bf16x8 fah[4], fal[4], fbh[4], fbl[4];
        #pragma unroll
        for (int t = 0; t < 4; t++) {
            fah[t] = *(const bf16x8*)&Ah[wm + t * 16 + ln][quad * 8];
            fal[t] = *(const bf16x8*)&Al[wm + t * 16 + ln][quad * 8];
            fbh[t] = *(const bf16x8*)&Bh[wn + t * 16 + ln][quad * 8];
            fbl[t] = *(const bf16x8*)&Bl[wn + t * 16 + ln][quad * 8];
        }
        #pragma unroll
        for (int mt = 0; mt < 4; mt++)
            #pragma unroll
            for (int nt = 0; nt < 4; nt++) {
                acc[mt][nt] = __builtin_amdgcn_mfma_f32_16x16x32_bf16(fal[mt], fbh[nt], acc[mt][nt], 0, 0, 0);
                acc[mt][nt] = __builtin_amdgcn_mfma_f32_16x16x32_bf16(fah[mt], fbl[nt], acc[mt][nt], 0, 0, 0);
                acc[mt][nt] = __builtin_amdgcn_mfma_f32_16x16x32_bf16(fah[mt], fbh[nt], acc[mt][nt], 0, 0, 0);
            }
    }
    #pragma unroll
    for (int mt = 0; mt < 4; mt++)
        #pragma unroll
        for (int nt = 0; nt < 4; nt++) {
            int cn = n0 + wn + nt * 16 + ln;
            if (cn < N) {
                #pragma unroll
                for (int r = 0; r < 4; r++) {
                    int cm = m0 + wm + mt * 16 + quad * 4 + r;
                    C[(size_t)cm * N + cn] = acc[mt][nt][r];
                }
            }
        }
}

// ---------------- fallback GEMM: fp32 A and B, in-kernel split ----------------
__global__ __launch_bounds__(256, 2)
void k_gemm_mfma(const float* __restrict__ A, const float* __restrict__ B,
                 float* __restrict__ C, int M, int N, int K) {
    __shared__ u16 Ah[128][LDKP], Al[128][LDKP];
    __shared__ u16 Bh[128][LDKP], Bl[128][LDKP];
    int n0 = blockIdx.x * 128, m0 = blockIdx.y * 128;
    int tid = threadIdx.x;
    int srow = tid >> 1, sk = (tid & 1) * 16;
    int lane = tid & 63, wave = tid >> 6;
    int wm = (wave >> 1) * 64, wn = (wave & 1) * 64;
    int ln = lane & 15, quad = lane >> 4;
    f32x4 acc[4][4];
    #pragma unroll
    for (int i = 0; i < 4; i++)
        #pragma unroll
        for (int j = 0; j < 4; j++) acc[i][j] = (f32x4){0.f, 0.f, 0.f, 0.f};
    const float* Ap = A + (size_t)(m0 + srow) * K + sk;
    const float* Bp = B + (size_t)(n0 + srow) * K + sk;
    bool bval = (n0 + srow) < N;
    for (int k0 = 0; k0 < K; k0 += 32) {
        float av[16], bv[16];
        #pragma unroll
        for (int i = 0; i < 4; i++) {
            *(float4*)&av[4 * i] = *(const float4*)(Ap + k0 + 4 * i);
            *(float4*)&bv[4 * i] = bval ? *(const float4*)(Bp + k0 + 4 * i)
                                        : make_float4(0.f, 0.f, 0.f, 0.f);
        }
        __syncthreads();
        #pragma unroll
        for (int g = 0; g < 2; g++) {
            unsigned hiA[4], loA[4], hiB[4], loB[4];
            #pragma unroll
            for (int j = 0; j < 4; j++) {
                float a0 = av[8 * g + 2 * j], a1 = av[8 * g + 2 * j + 1];
                unsigned short h0 = f2bf(a0), h1 = f2bf(a1);
                unsigned short l0 = f2bf(a0 - bf2f(h0)), l1 = f2bf(a1 - bf2f(h1));
                hiA[j] = (unsigned)h0 | ((unsigned)h1 << 16);
                loA[j] = (unsigned)l0 | ((unsigned)l1 << 16);
                float b0 = bv[8 * g + 2 * j], b1 = bv[8 * g + 2 * j + 1];
                unsigned short g0 = f2bf(b0), g1 = f2bf(b1);
                unsigned short m0s = f2bf(b0 - bf2f(g0)), m1s = f2bf(b1 - bf2f(g1));
                hiB[j] = (unsigned)g0 | ((unsigned)g1 << 16);
                loB[j] = (unsigned)m0s | ((unsigned)m1s << 16);
            }
            *(uint4*)&Ah[srow][sk + 8 * g] = *(uint4*)hiA;
            *(uint4*)&Al[srow][sk + 8 * g] = *(uint4*)loA;
            *(uint4*)&Bh[srow][sk + 8 * g] = *(uint4*)hiB;
            *(uint4*)&Bl[srow][sk + 8 * g] = *(uint4*)loB;
        }
        __syncthreads();
        bf16x8 fah[4], fal[4], fbh[4], fbl[4];
        #pragma unroll
        for (int t = 0; t < 4; t++) {
            fah[t] = *(const bf16x8*)&Ah[wm + t * 16 + ln][quad * 8];
            fal[t] = *(const bf16x8*)&Al[wm + t * 16 + ln][quad * 8];
            fbh[t] = *(const bf16x8*)&Bh[wn + t * 16 + ln][quad * 8];
            fbl[t] = *(const bf16x8*)&Bl[wn + t * 16 + ln][quad * 8];
        }
        #pragma unroll
        for (int mt = 0; mt < 4; mt++)
            #pragma unroll
            for (int nt = 0; nt < 4; nt++) {
                acc[mt][nt] = __builtin_amdgcn_mfma_f32_16x16x32_bf16(fal[mt], fbh[nt], acc[mt][nt], 0, 0, 0);
                acc[mt][nt] = __builtin_amdgcn_mfma_f32_16x16x32_bf16(fah[mt], fbl[nt], acc[mt][nt], 0, 0, 0);
                acc[mt][nt] = __builtin_amdgcn_mfma_f32_16x16x32_bf16(fah[mt], fbh[nt], acc[mt][nt], 0, 0, 0);
            }
    }
    #pragma unroll
    for (int mt = 0; mt < 4; mt++)
        #pragma unroll
        for (int nt = 0; nt < 4; nt++) {
            int cn = n0 + wn + nt * 16 + ln;
            if (cn < N) {
                #pragma unroll
                for (int r = 0; r < 4; r++) {
                    int cm = m0 + wm + mt * 16 + quad * 4 + r;
                    C[(size_t)cm * N + cn] = acc[mt][nt][r];
                }
            }
        }
}

// ---------------- pack x (split planes) / legacy pack x / pack w ----------------
__global__ __launch_bounds__(256)
void k_pack_x2(const float* __restrict__ x, u16* __restrict__ xh,
               u16* __restrict__ xl) {
    size_t idx = (size_t)blockIdx.x * 256 + threadIdx.x;
    int k = (int)(idx & 63);
    size_t m = idx >> 6;
    float v = (k < D_IN) ? x[m * D_IN + k] : 0.f;
    u16 hi, lo; split2(v, hi, lo);
    xh[idx] = hi; xl[idx] = lo;
}
__global__ __launch_bounds__(256)
void k_pack_x(const float* __restrict__ x, float* __restrict__ xp) {
    size_t idx = (size_t)blockIdx.x * 256 + threadIdx.x;
    int k = (int)(idx & 63);
    size_t m = idx >> 6;
    xp[idx] = (k < D_IN) ? x[m * D_IN + k] : 0.f;
}
__global__ __launch_bounds__(256)
void k_pack_w(const float* __restrict__ w, float* __restrict__ wp) {
    int idx = blockIdx.x * 256 + threadIdx.x;
    int k = idx & 63, n = idx >> 6;
    wp[idx] = (k < D_IN) ? w[n * D_IN + k] : 0.f;
}

// ---------------- h = LN(pre + in_b) -> split planes ----------------
__global__ __launch_bounds__(256)
void k_lnio2(const float* __restrict__ pre, const float* __restrict__ bias,
             const float* __restrict__ gw, const float* __restrict__ gb,
             u16* __restrict__ Hh, u16* __restrict__ Hl) {
    int m = blockIdx.x, o = threadIdx.x;
    __shared__ float sred[8];
    float v = pre[(size_t)m * D_MODEL + o] + bias[o];
    float2 s = block_reduce2(v, v * v, sred);
    float mu = s.x * (1.f / D_MODEL);
    float var = s.y * (1.f / D_MODEL) - mu * mu;
    float hv = (v - mu) * rsqrtf(var + EPS) * gw[o] + gb[o];
    u16 hi, lo; split2(hv, hi, lo);
    Hh[(size_t)m * D_MODEL + o] = hi;
    Hl[(size_t)m * D_MODEL + o] = lo;
}
// fallback fp32 variant
__global__ __launch_bounds__(256)
void k_lnio(const float* __restrict__ pre, const float* __restrict__ bias,
            const float* __restrict__ gw, const float* __restrict__ gb,
            float* __restrict__ h) {
    int m = blockIdx.x, o = threadIdx.x;
    __shared__ float sred[8];
    float v = pre[(size_t)m * D_MODEL + o] + bias[o];
    float2 s = block_reduce2(v, v * v, sred);
    float mu = s.x * (1.f / D_MODEL);
    float var = s.y * (1.f / D_MODEL) - mu * mu;
    h[(size_t)m * D_MODEL + o] = (v - mu) * rsqrtf(var + EPS) * gw[o] + gb[o];
}

// ---------------- conv (causal depthwise k=4) + silu + dt ----------------
__global__ __launch_bounds__(256)
void k_conv(const float* __restrict__ xbc, const float* __restrict__ cw,
            const float* __restrict__ cb, const float* __restrict__ dtb,
            float* __restrict__ xs, float* __restrict__ Bm, float* __restrict__ Cm,
            float* __restrict__ dtv) {
    int m = blockIdx.x;
    int l = m & (LSEQ - 1);
    int tid = threadIdx.x;
    #pragma unroll
    for (int it = 0; it < 3; it++) {
        int c = tid + it * 256;
        float acc = cb[c];
        #pragma unroll
        for (int k = 0; k < DCONV; k++) {
            int lp = l - (DCONV - 1) + k;
            if (lp >= 0)
                acc = fmaf(cw[k * CONV_CH + c],
                           xbc[(size_t)(m - (DCONV - 1) + k) * XBCDT + c], acc);
        }
        float v = silu_f(acc);
        if (c < D_INNER) xs[(size_t)m * D_INNER + c] = v;
        else if (c < D_INNER + D_STATE) Bm[(size_t)m * D_STATE + (c - D_INNER)] = v;
        else Cm[(size_t)m * D_STATE + (c - D_INNER - D_STATE)] = v;
    }
    if (tid < NH) {
        float draw = xbc[(size_t)m * XBCDT + CONV_CH + tid] + dtb[tid];
        float dt = draw > 20.f ? draw : log1pf(expf(draw));
        dtv[m * NH + tid] = dt;
    }
}

// ---------------- Pass A: segment-local scan (round-9 proven) ----------------
__global__ __launch_bounds__(256, 4)
void k_scan_seg(const float* __restrict__ xs, const float* __restrict__ Bm,
                const float* __restrict__ Cm, const float* __restrict__ dtv,
                const float* __restrict__ Alog, const float* __restrict__ Dvec,
                float* __restrict__ y, float* __restrict__ F,
                float* __restrict__ cumdA) {
    int blk = blockIdx.x;
    int bh = blk >> 2;
    int seg = blk & (SSEG - 1);
    int b = bh >> 3, hh = bh & 7;
    int tid = threadIdx.x;
    int q = tid & 7;
    int pl = tid >> 3;
    int q2 = q >> 1;
    __shared__ __align__(16) float sBC[2 * CT * 128];
    __shared__ __align__(16) float sX[CT][HP];
    __shared__ float sdt[CT], sdA[CT], srdA[CT];
    float h0[16], h1[16];
    #pragma unroll
    for (int i = 0; i < 16; i++) { h0[i] = 0.f; h1[i] = 0.f; }
    float Dh = Dvec[hh];
    float Ahv = -expf(Alog[hh]);
    float c_run = 1.f;
    const size_t base = (size_t)b * LSEQ + (size_t)seg * TSEG;
    int col = tid & 127, half = tid >> 7;
    int sw = swz8(col);
    int xc = tid & 63, xh = tid >> 6;

    float rB[8], rC[8], rX[4], rdt = 0.f;
    #pragma unroll
    for (int u = 0; u < 8; u++) {
        size_t m = base + 2 * u + half;
        rB[u] = Bm[m * D_STATE + col];
        rC[u] = Cm[m * D_STATE + col];
    }
    #pragma unroll
    for (int u = 0; u < 4; u++)
        rX[u] = xs[(base + 4 * u + xh) * D_INNER + hh * HP + xc];
    if (tid < CT) rdt = dtv[(base + tid) * NH + hh];

    for (int c0 = 0; c0 < TSEG; c0 += CT) {
        #pragma unroll
        for (int u = 0; u < 8; u++) {
            int s = 2 * u + half;
            sBC[s * 128 + sw] = rB[u];
            sBC[(CT + s) * 128 + sw] = rC[u];
        }
        #pragma unroll
        for (int u = 0; u < 4; u++)
            sX[4 * u + xh][xc] = rX[u];
        if (tid < CT) {
            float e = fmaxf(rdt * Ahv, -37.f);
            sdt[tid] = rdt;
            sdA[tid] = expf(e);
            srdA[tid] = expf(-e);
        }
        __syncthreads();
        if (c0 + CT < TSEG) {
            size_t nb = base + c0 + CT;
            #pragma unroll
            for (int u = 0; u < 8; u++) {
                size_t m = nb + 2 * u + half;
                rB[u] = Bm[m * D_STATE + col];
                rC[u] = Cm[m * D_STATE + col];
            }
            #pragma unroll
            for (int u = 0; u < 4; u++)
                rX[u] = xs[(nb + 4 * u + xh) * D_INNER + hh * HP + xc];
            if (tid < CT) rdt = dtv[(nb + tid) * NH + hh];
        }
        if (tid == 0) {
            float cg = c_run;
            for (int s = 0; s < CT; s++) {
                cg *= sdA[s];
                cumdA[(base + c0 + s) * NH + hh] = cg;
            }
            c_run = cg;
        }
        float cc = 1.f, rc = 1.f;
        #pragma unroll
        for (int s = 0; s < CT; s++) {
            float dAl = sdA[s], dtl = sdt[s];
            float ccn = cc * dAl;
            if (ccn < 1e-18f) {
                #pragma unroll
                for (int i = 0; i < 16; i++) { h0[i] *= cc; h1[i] *= cc; }
                rc = srdA[s];
                ccn = dAl;
            } else {
                rc *= srdA[s];
            }
            cc = ccn;
            float xv0 = sX[s][pl];
            float xv1 = sX[s][pl + 32];
            float dr = dtl * rc;
            float t0 = dr * xv0, t1 = dr * xv1;
            float ya0 = 0.f, yb0 = 0.f, ya1 = 0.f, yb1 = 0.f;
            #pragma unroll
            for (int i = 0; i < 4; i++) {
                int off = (q << 4) + (((i + q2) & 3) << 2);
                float4 bv = *(const float4*)&sBC[s * 128 + off];
                float4 cv = *(const float4*)&sBC[(CT + s) * 128 + off];
                h0[4*i+0] = fmaf(t0, bv.x, h0[4*i+0]); ya0 = fmaf(h0[4*i+0], cv.x, ya0);
                h0[4*i+1] = fmaf(t0, bv.y, h0[4*i+1]); yb0 = fmaf(h0[4*i+1], cv.y, yb0);
                h0[4*i+2] = fmaf(t0, bv.z, h0[4*i+2]); ya0 = fmaf(h0[4*i+2], cv.z, ya0);
                h0[4*i+3] = fmaf(t0, bv.w, h0[4*i+3]); yb0 = fmaf(h0[4*i+3], cv.w, yb0);
                h1[4*i+0] = fmaf(t1, bv.x, h1[4*i+0]); ya1 = fmaf(h1[4*i+0], cv.x, ya1);
                h1[4*i+1] = fmaf(t1, bv.y, h1[4*i+1]); yb1 = fmaf(h1[4*i+1], cv.y, yb1);
                h1[4*i+2] = fmaf(t1, bv.z, h1[4*i+2]); ya1 = fmaf(h1[4*i+2], cv.z, ya1);
                h1[4*i+3] = fmaf(t1, bv.w, h1[4*i+3]); yb1 = fmaf(h1[4*i+3], cv.w, yb1);
            }
            float yp0 = ya0 + yb0;
            float yp1 = ya1 + yb1;
            yp0 += __shfl_xor(yp0, 1);  yp1 += __shfl_xor(yp1, 1);
            yp0 += __shfl_xor(yp0, 2);  yp1 += __shfl_xor(yp1, 2);
            yp0 += __shfl_xor(yp0, 4);  yp1 += __shfl_xor(yp1, 4);
            if (q == 0) {
                size_t row = (base + c0 + s) * D_INNER + hh * HP;
                y[row + pl]      = fmaf(Dh, xv0, cc * yp0);
                y[row + pl + 32] = fmaf(Dh, xv1, cc * yp1);
            }
            if ((s & (RS - 1)) == RS - 1) {
                #pragma unroll
                for (int i = 0; i < 16; i++) { h0[i] *= cc; h1[i] *= cc; }
                cc = 1.f; rc = 1.f;
            }
        }
        __syncthreads();
    }
    if (seg < SSEG - 1) {
        float* F0 = F + (((size_t)bh * (SSEG - 1) + seg) * HP + pl) * D_STATE + (q << 4);
        float* F1 = F + (((size_t)bh * (SSEG - 1) + seg) * HP + pl + 32) * D_STATE + (q << 4);
        #pragma unroll
        for (int i = 0; i < 4; i++) {
            *(float4*)(F0 + 4 * i) = make_float4(h0[4*i], h0[4*i+1], h0[4*i+2], h0[4*i+3]);
            *(float4*)(F1 + 4 * i) = make_float4(h1[4*i], h1[4*i+1], h1[4*i+2], h1[4*i+3]);
        }
    }
}

// ---------------- Pass C (fused combine), round-9 proven ----------------
__global__ __launch_bounds__(256, 4)
void k_seg_fix(const float* __restrict__ Cm, const float* __restrict__ cumdA,
               const float* __restrict__ F, float* __restrict__ y) {
    int blk = blockIdx.x;
    int bh = blk / (SSEG - 1);
    int seg = blk - bh * (SSEG - 1) + 1;
    int b = bh >> 3, hh = bh & 7;
    int tid = threadIdx.x;
    int q = tid & 7;
    int pl = tid >> 3;
    int q2 = q >> 1;
    float g0[16], g1[16];
    #pragma unroll
    for (int i = 0; i < 16; i++) { g0[i] = 0.f; g1[i] = 0.f; }
    for (int s = 0; s < seg; s++) {
        float P = cumdA[((size_t)b * LSEQ + (size_t)(s + 1) * TSEG - 1) * NH + hh];
        const float* F0 = F + (((size_t)bh * (SSEG - 1) + s) * HP + pl) * D_STATE + (q << 4);
        const float* F1 = F + (((size_t)bh * (SSEG - 1) + s) * HP + pl + 32) * D_STATE + (q << 4);
        #pragma unroll
        for (int i = 0; i < 4; i++) {
            float4 f0 = *(const float4*)(F0 + 4 * i);
            float4 f1 = *(const float4*)(F1 + 4 * i);
            g0[4*i+0] = fmaf(g0[4*i+0], P, f0.x);
            g0[4*i+1] = fmaf(g0[4*i+1], P, f0.y);
            g0[4*i+2] = fmaf(g0[4*i+2], P, f0.z);
            g0[4*i+3] = fmaf(g0[4*i+3], P, f0.w);
            g1[4*i+0] = fmaf(g1[4*i+0], P, f1.x);
            g1[4*i+1] = fmaf(g1[4*i+1], P, f1.y);
            g1[4*i+2] = fmaf(g1[4*i+2], P, f1.z);
            g1[4*i+3] = fmaf(g1[4*i+3], P, f1.w);
        }
    }
    __shared__ __align__(16) float sC[CT * 128];
    __shared__ float scd[CT];
    const size_t base = (size_t)b * LSEQ + (size_t)seg * TSEG;
    int col = tid & 127, half = tid >> 7;
    int sw = swz8(col);
    float rC[8], rcd = 0.f;
    #pragma unroll
    for (int u = 0; u < 8; u++)
        rC[u] = Cm[(base + 2 * u + half) * D_STATE + col];
    if (tid < CT) rcd = cumdA[(base + tid) * NH + hh];

    for (int c0 = 0; c0 < TSEG; c0 += CT) {
        #pragma unroll
        for (int u = 0; u < 8; u++)
            sC[(2 * u + half) * 128 + sw] = rC[u];
        if (tid < CT) scd[tid] = rcd;
        __syncthreads();
        if (c0 + CT < TSEG) {
            size_t nb = base + c0 + CT;
            #pragma unroll
            for (int u = 0; u < 8; u++)
                rC[u] = Cm[(nb + 2 * u + half) * D_STATE + col];
            if (tid < CT) rcd = cumdA[(nb + tid) * NH + hh];
        }
        #pragma unroll 1
        for (int s = 0; s < CT; s++) {
            float ya0 = 0.f, yb0 = 0.f, ya1 = 0.f, yb1 = 0.f;
            #pragma unroll
            for (int i = 0; i < 4; i++) {
                int off = (q << 4) + (((i + q2) & 3) << 2);
                float4 cv = *(const float4*)&sC[s * 128 + off];
                ya0 = fmaf(g0[4*i+0], cv.x, ya0);
                yb0 = fmaf(g0[4*i+1], cv.y, yb0);
                ya0 = fmaf(g0[4*i+2], cv.z, ya0);
                yb0 = fmaf(g0[4*i+3], cv.w, yb0);
                ya1 = fmaf(g1[4*i+0], cv.x, ya1);
                yb1 = fmaf(g1[4*i+1], cv.y, yb1);
                ya1 = fmaf(g1[4*i+2], cv.z, ya1);
                yb1 = fmaf(g1[4*i+3], cv.w, yb1);
            }
            float yp0 = ya0 + yb0;
            float yp1 = ya1 + yb1;
            yp0 += __shfl_xor(yp0, 1);  yp1 += __shfl_xor(yp1, 1);
            yp0 += __shfl_xor(yp0, 2);  yp1 += __shfl_xor(yp1, 2);
            yp0 += __shfl_xor(yp0, 4);  yp1 += __shfl_xor(yp1, 4);
            if (q == 0) {
                size_t row = (base + c0 + s) * D_INNER + hh * HP;
                y[row + pl]      += scd[s] * yp0;
                y[row + pl + 32] += scd[s] * yp1;
            }
        }
        __syncthreads();
    }
}

// ---------------- gated RMSNorm -> split planes ----------------
__global__ __launch_bounds__(256)
void k_gate2(const float* __restrict__ y, const float* __restrict__ zbuf,
             const float* __restrict__ nw, u16* __restrict__ Yh,
             u16* __restrict__ Yl) {
    int m = blockIdx.x, tid = threadIdx.x;
    __shared__ float sred[8];
    float g[2];
    #pragma unroll
    for (int j = 0; j < 2; j++) {
        int d = tid + j * 256;
        float z = zbuf[(size_t)m * D_INNER + d];
        g[j] = y[(size_t)m * D_INNER + d] * silu_f(z);
    }
    float2 s = block_reduce2(g[0] * g[0] + g[1] * g[1], 0.f, sred);
    float r = rsqrtf(s.x * (1.f / D_INNER) + EPS);
    #pragma unroll
    for (int j = 0; j < 2; j++) {
        int d = tid + j * 256;
        float v = g[j] * r * nw[d];
        u16 hi, lo; split2(v, hi, lo);
        Yh[(size_t)m * D_INNER + d] = hi;
        Yl[(size_t)m * D_INNER + d] = lo;
    }
}
// fallback fp32 variant
__global__ __launch_bounds__(256)
void k_gate(float* __restrict__ y, const float* __restrict__ zbuf,
            const float* __restrict__ nw) {
    int m = blockIdx.x, tid = threadIdx.x;
    __shared__ float sred[8];
    float g[2];
    #pragma unroll
    for (int j = 0; j < 2; j++) {
        int d = tid + j * 256;
        float z = zbuf[(size_t)m * D_INNER + d];
        g[j] = y[(size_t)m * D_INNER + d] * silu_f(z);
    }
    float2 s = block_reduce2(g[0] * g[0] + g[1] * g[1], 0.f, sred);
    float r = rsqrtf(s.x * (1.f / D_INNER) + EPS);
    #pragma unroll
    for (int j = 0; j < 2; j++) {
        int d = tid + j * 256;
        y[(size_t)m * D_INNER + d] = g[j] * r * nw[d];
    }
}

// ---------------- h = LN(mo + h); h kept as split planes ----------------
__global__ __launch_bounds__(256)
void k_addln2(const float* __restrict__ mo, u16* __restrict__ Hh,
              u16* __restrict__ Hl, const float* __restrict__ w,
              const float* __restrict__ bias) {
    int m = blockIdx.x, o = threadIdx.x;
    __shared__ float sred[8];
    size_t idx = (size_t)m * D_MODEL + o;
    float hold = bf2f(Hh[idx]) + bf2f(Hl[idx]);
    float v = mo[idx] + hold;
    float2 s = block_reduce2(v, v * v, sred);
    float mu = s.x * (1.f / D_MODEL);
    float var = s.y * (1.f / D_MODEL) - mu * mu;
    float hv = (v - mu) * rsqrtf(var + EPS) * w[o] + bias[o];
    u16 hi, lo; split2(hv, hi, lo);
    Hh[idx] = hi; Hl[idx] = lo;
}
// fallback fp32 variant
__global__ __launch_bounds__(256)
void k_addln(const float* __restrict__ mo, float* __restrict__ h,
             const float* __restrict__ w, const float* __restrict__ bias) {
    int m = blockIdx.x, o = threadIdx.x;
    __shared__ float sred[8];
    float v = mo[(size_t)m * D_MODEL + o] + h[(size_t)m * D_MODEL + o];
    float2 s = block_reduce2(v, v * v, sred);
    float mu = s.x * (1.f / D_MODEL);
    float var = s.y * (1.f / D_MODEL) - mu * mu;
    h[(size_t)m * D_MODEL + o] = (v - mu) * rsqrtf(var + EPS) * w[o] + bias[o];
}

// ---------------- pooled partial sums ----------------
__global__ __launch_bounds__(256)
void k_pool_part2(const u16* __restrict__ Hh, const u16* __restrict__ Hl,
                  const int* __restrict__ len, float* __restrict__ part) {
    int blk = blockIdx.x;
    int b = blk >> 4, ch = blk & 15;
    int d = threadIdx.x;
    int Lb = len[b];
    int l0 = ch * 64;
    int le = min(l0 + 64, Lb);
    float acc = 0.f;
    for (int l = l0; l < le; l++) {
        size_t idx = ((size_t)b * LSEQ + l) * D_MODEL + d;
        acc += bf2f(Hh[idx]) + bf2f(Hl[idx]);
    }
    part[(size_t)blk * D_MODEL + d] = acc;
}
__global__ __launch_bounds__(256)
void k_pool_part(const float* __restrict__ h, const int* __restrict__ len,
                 float* __restrict__ part) {
    int blk = blockIdx.x;
    int b = blk >> 4, ch = blk & 15;
    int d = threadIdx.x;
    int Lb = len[b];
    int l0 = ch * 64;
    int le = min(l0 + 64, Lb);
    float acc = 0.f;
    for (int l = l0; l < le; l++) acc += h[((size_t)b * LSEQ + l) * D_MODEL + d];
    part[(size_t)blk * D_MODEL + d] = acc;
}

// ---------------- final head ----------------
__global__ __launch_bounds__(256)
void k_head(const float* __restrict__ part, const int* __restrict__ len,
            const float* __restrict__ hw, const float* __restrict__ hb,
            float* __restrict__ out) {
    int b = blockIdx.x, d = threadIdx.x;
    __shared__ float sp[D_MODEL];
    float a = 0.f;
    #pragma unroll
    for (int c = 0; c < 16; c++) a += part[(size_t)(b * 16 + c) * D_MODEL + d];
    sp[d] = a / (float)len[b];
    __syncthreads();
    if (d < N_CLS) {
        float o = hb[d];
        const float* wr = hw + (size_t)d * D_MODEL;
        #pragma unroll 8
        for (int k = 0; k < D_MODEL; k++) o = fmaf(sp[k], wr[k], o);
        out[b * N_CLS + d] = o;
    }
}

extern "C" void kernel_launch(void* const* d_in, const int* in_sizes, int n_in,
                              void* d_out, int out_size, void* d_ws, size_t ws_size,
                              hipStream_t stream) {
    const float* x      = (const float*)d_in[0];
    const float* in_w   = (const float*)d_in[1];
    const float* in_b   = (const float*)d_in[2];
    const float* lnin_w = (const float*)d_in[3];
    const float* lnin_b = (const float*)d_in[4];
    const float* inproj = (const float*)d_in[5];
    const float* conv_w = (const float*)d_in[6];
    const float* conv_b = (const float*)d_in[7];
    const float* dt_bias= (const float*)d_in[8];
    const float* A_log  = (const float*)d_in[9];
    const float* Dv     = (const float*)d_in[10];
    const float* norm_w = (const float*)d_in[11];
    const float* outp_w = (const float*)d_in[12];
    const float* ln_w   = (const float*)d_in[13];
    const float* ln_b   = (const float*)d_in[14];
    const float* head_w = (const float*)d_in[15];
    const float* head_b = (const float*)d_in[16];
    const int*   lengths= (const int*)d_in[17];
    float* out = (float*)d_out;

    float* ws    = (float*)d_ws;
    float* h     = ws;                              // fp32 h (fallback) OR Hhi/Hlo planes
    float* buf1  = h    + (size_t)NTOK * D_MODEL;
    float* xs    = buf1 + (size_t)NTOK * XBCDT;
    float* Bm    = xs   + (size_t)NTOK * D_INNER;
    float* Cm    = Bm   + (size_t)NTOK * D_STATE;
    float* dtv   = Cm   + (size_t)NTOK * D_STATE;
    float* cumdA = dtv  + (size_t)NTOK * NH;
    float* zbuf  = buf1;
    float* F     = buf1 + (size_t)NTOK * D_INNER;
    float* pre   = buf1 + (size_t)NTOK * 64;
    float* poolp = buf1;
    unsigned short* WP = (unsigned short*)(ws + WS_BASE);
    bool use_pk = (ws_size >= WS_NEED);

    // main-path plane views (aliasing audited):
    // Hhi+Hlo = NTOK*512 u16 = NTOK*256 floats -> exactly the h region.
    u16* Hhi = (u16*)h;
    u16* Hlo = Hhi + (size_t)NTOK * D_MODEL;
    // Yhi = NTOK*512 u16 = NTOK*256 floats -> dead F region (buf1[512..768) of 776).
    // Ylo = NTOK*512 u16 = NTOK*256 floats -> dead Bm+Cm region (exact fit).
    u16* Yhi = (u16*)(buf1 + (size_t)NTOK * D_INNER);
    u16* Ylo = (u16*)Bm;
    float* mo2 = xs;                         // out-proj result over dead xs
    u16* xphi = (u16*)buf1;                  // NTOK*64 u16
    u16* xplo = xphi + (size_t)NTOK * 64;    // total NTOK*64 floats < pre offset

    dim3 gIO(D_MODEL / 128, NTOK / 128);
    dim3 g1a((XBCDT + 127) / 128, NTOK / 128);
    dim3 g1b(D_INNER / 128, NTOK / 128);
    int gScan = BSZ * NH * SSEG;
    int gFix  = BSZ * NH * (SSEG - 1);

    if (use_pk) {
        k_pack_weights<<<TOTPK / 256, 256, 0, stream>>>(in_w, inproj, outp_w, WP);
        k_pack_x2<<<NTOK * 64 / 256, 256, 0, stream>>>(x, xphi, xplo);
        k_gemm_bb<<<gIO, 256, 0, stream>>>(xphi, xplo, WP + IN_HI, WP + IN_LO, pre,
                                           NTOK, D_MODEL, 64);
        k_lnio2<<<NTOK, 256, 0, stream>>>(pre, in_b, lnin_w, lnin_b, Hhi, Hlo);
        for (int i = 0; i < NL; i++) {
            const u16* iph = WP + IP_HI + (size_t)i * PROJ * D_MODEL;
            const u16* ipl = WP + IP_LO + (size_t)i * PROJ * D_MODEL;
            k_gemm_bb<<<g1a, 256, 0, stream>>>(Hhi, Hlo,
                                               iph + (size_t)D_INNER * D_MODEL,
                                               ipl + (size_t)D_INNER * D_MODEL,
                                               buf1, NTOK, XBCDT, D_MODEL);
            k_conv<<<NTOK, 256, 0, stream>>>(buf1, conv_w + i * DCONV * CONV_CH,
                                             conv_b + i * CONV_CH, dt_bias + i * NH,
                                             xs, Bm, Cm, dtv);
            k_gemm_bb<<<g1b, 256, 0, stream>>>(Hhi, Hlo, iph, ipl, zbuf,
                                               NTOK, D_INNER, D_MODEL);
            k_scan_seg<<<gScan, 256, 0, stream>>>(xs, Bm, Cm, dtv,
                                                  A_log + i * NH, Dv + i * NH,
                                                  xs, F, cumdA);
            k_seg_fix<<<gFix, 256, 0, stream>>>(Cm, cumdA, F, xs);
            k_gate2<<<NTOK, 256, 0, stream>>>(xs, zbuf, norm_w + i * D_INNER, Yhi, Ylo);
            k_gemm_bb<<<gIO, 256, 0, stream>>>(Yhi, Ylo,
                                               WP + OP_HI + (size_t)i * D_MODEL * D_INNER,
                                               WP + OP_LO + (size_t)i * D_MODEL * D_INNER,
                                               mo2, NTOK, D_MODEL, D_INNER);
            k_addln2<<<NTOK, 256, 0, stream>>>(mo2, Hhi, Hlo,
                                               ln_w + i * D_MODEL, ln_b + i * D_MODEL);
        }
        k_pool_part2<<<BSZ * 16, 256, 0, stream>>>(Hhi, Hlo, lengths, poolp);
    } else {
        float* wp = Bm;
        float* xp = buf1;
        float* mo = Bm;
        k_pack_x<<<NTOK * 64 / 256, 256, 0, stream>>>(x, xp);
        k_pack_w<<<64, 256, 0, stream>>>(in_w, wp);
        k_gemm_mfma<<<gIO, 256, 0, stream>>>(xp, wp, pre, NTOK, D_MODEL, 64);
        k_lnio<<<NTOK, 256, 0, stream>>>(pre, in_b, lnin_w, lnin_b, h);
        for (int i = 0; i < NL; i++) {
            const float* W = inproj + (size_t)i * PROJ * D_MODEL;
            k_gemm_mfma<<<g1a, 256, 0, stream>>>(h, W + (size_t)D_INNER * D_MODEL,
                                                 buf1, NTOK, XBCDT, D_MODEL);
            k_conv<<<NTOK, 256, 0, stream>>>(buf1, conv_w + i * DCONV * CONV_CH,
                                             conv_b + i * CONV_CH, dt_bias + i * NH,
                                             xs, Bm, Cm, dtv);
            k_gemm_mfma<<<g1b, 256, 0, stream>>>(h, W, zbuf, NTOK, D_INNER, D_MODEL);
            k_scan_seg<<<gScan, 256, 0, stream>>>(xs, Bm, Cm, dtv,
                                                  A_log + i * NH, Dv + i * NH,
                                                  xs, F, cumdA);
            k_seg_fix<<<gFix, 256, 0, stream>>>(Cm, cumdA, F, xs);
            k_gate<<<NTOK, 256, 0, stream>>>(xs, zbuf, norm_w + i * D_INNER);
            k_gemm_mfma<<<gIO, 256, 0, stream>>>(xs, outp_w + (size_t)i * D_MODEL * D_INNER,
                                                 mo, NTOK, D_MODEL, D_INNER);
            k_addln<<<NTOK, 256, 0, stream>>>(mo, h, ln_w + i * D_MODEL, ln_b + i * D_MODEL);
        }
        k_pool_part<<<BSZ * 16, 256, 0, stream>>>(h, lengths, poolp);
    }

    k_head<<<BSZ, 256, 0, stream>>>(poolp, lengths, head_w, head_b, out);
}

// Round 12
// 2697.235 us; speedup vs baseline: 1.0116x; 1.0116x over previous
//
#include <hip/hip_runtime.h>
#include <math.h>

#define D_IN 63
#define D_MODEL 256
#define N_CLS 14
#define NL 4
#define D_INNER 512
#define D_STATE 128
#define NH 8
#define HP 64
#define DCONV 4
#define CONV_CH 768
#define PROJ 1288
#define XBCDT 776
#define EPS 1e-5f
#define BSZ 32
#define LSEQ 1024
#define NTOK (BSZ*LSEQ)

#define SSEG 4
#define TSEG (LSEQ/SSEG)
#define CT 16
#define RS 8

// weight-pack region (ushort offsets)
#define S_IN   16384
#define S_IP   1318912
#define S_OP   524288
#define IN_HI  0
#define IN_LO  16384
#define IP_HI  32768
#define IP_LO  (32768 + S_IP)
#define OP_HI  (32768 + 2*S_IP)
#define OP_LO  (OP_HI + S_OP)
#define TOTPK  (S_IN + S_IP + S_OP)
#define WS_BASE ((size_t)NTOK * 1816)
#define WS_NEED ((WS_BASE + (size_t)TOTPK) * 4)

typedef __attribute__((ext_vector_type(8))) short bf16x8;
typedef __attribute__((ext_vector_type(4))) float f32x4;
typedef unsigned short u16;

__device__ __forceinline__ float silu_f(float x) { return x / (1.f + expf(-x)); }

__device__ __forceinline__ unsigned short f2bf(float x) {
    union { float f; unsigned u; } v; v.f = x;
    unsigned r = v.u + 0x7FFFu + ((v.u >> 16) & 1u);
    return (unsigned short)(r >> 16);
}
__device__ __forceinline__ float bf2f(unsigned short h) {
    union { float f; unsigned u; } v; v.u = ((unsigned)h) << 16; return v.f;
}

// swizzle for 8 groups of 16 values (proven 0-conflict)
__device__ __forceinline__ int swz8(int n) {
    int g = n >> 4, j = (n >> 2) & 3, e = n & 3;
    return (g << 4) + (((j + (g >> 1)) & 3) << 2) + e;
}

__device__ __forceinline__ float2 block_reduce2(float a, float b, float* sred) {
    #pragma unroll
    for (int off = 32; off >= 1; off >>= 1) {
        a += __shfl_xor(a, off);
        b += __shfl_xor(b, off);
    }
    int wid = threadIdx.x >> 6, lane = threadIdx.x & 63;
    if (lane == 0) { sred[wid * 2] = a; sred[wid * 2 + 1] = b; }
    __syncthreads();
    a = sred[0] + sred[2] + sred[4] + sred[6];
    b = sred[1] + sred[3] + sred[5] + sred[7];
    __syncthreads();
    return make_float2(a, b);
}

// ---------------- pack all weights to bf16 hi/lo planes ----------------
__global__ __launch_bounds__(256)
void k_pack_weights(const float* __restrict__ in_w, const float* __restrict__ inproj,
                    const float* __restrict__ outp, u16* __restrict__ WP) {
    int idx = blockIdx.x * 256 + threadIdx.x;
    float v; int hi_off, lo_off;
    if (idx < S_IN) {
        int n = idx >> 6, k = idx & 63;
        v = (k < D_IN) ? in_w[n * D_IN + k] : 0.f;
        hi_off = IN_HI + idx; lo_off = IN_LO + idx;
    } else if (idx < S_IN + S_IP) {
        int j = idx - S_IN;
        v = inproj[j];
        hi_off = IP_HI + j; lo_off = IP_LO + j;
    } else {
        int j = idx - S_IN - S_IP;
        v = outp[j];
        hi_off = OP_HI + j; lo_off = OP_LO + j;
    }
    unsigned short h = f2bf(v);
    unsigned short l = f2bf(v - bf2f(h));
    WP[hi_off] = h; WP[lo_off] = l;
}

// ---------------- MFMA GEMM, A fp32 (in-kernel trunc split), B pre-packed ----------
// K-loop register-prefetch: next tile's global loads issue right after the
// second barrier, consumed one full MFMA section later (scan-proven pattern).
#define LDKP 40
__global__ __launch_bounds__(256, 2)
void k_gemm_as(const float* __restrict__ A, const u16* __restrict__ Bhg,
               const u16* __restrict__ Blg, float* __restrict__ C,
               int M, int N, int K) {
    __shared__ u16 Ah[128][LDKP], Al[128][LDKP];
    __shared__ u16 Bh[128][LDKP], Bl[128][LDKP];
    int n0 = blockIdx.x * 128, m0 = blockIdx.y * 128;
    int tid = threadIdx.x;
    int srow = tid >> 1, sk = (tid & 1) * 16;
    int lane = tid & 63, wave = tid >> 6;
    int wm = (wave >> 1) * 64, wn = (wave & 1) * 64;
    int ln = lane & 15, quad = lane >> 4;
    f32x4 acc[4][4];
    #pragma unroll
    for (int i = 0; i < 4; i++)
        #pragma unroll
        for (int j = 0; j < 4; j++) acc[i][j] = (f32x4){0.f, 0.f, 0.f, 0.f};
    const float* Ap = A + (size_t)(m0 + srow) * K + sk;
    const u16* Bhp = Bhg + (size_t)(n0 + srow) * K + sk;
    const u16* Blp = Blg + (size_t)(n0 + srow) * K + sk;
    bool bval = (n0 + srow) < N;
    uint4 z4 = make_uint4(0u, 0u, 0u, 0u);
    // staging registers
    float av[16];
    uint4 bh0, bh1, bl0, bl1;
    // prologue: load tile 0
    #pragma unroll
    for (int i = 0; i < 4; i++)
        *(float4*)&av[4 * i] = *(const float4*)(Ap + 4 * i);
    bh0 = bval ? *(const uint4*)(Bhp) : z4;
    bh1 = bval ? *(const uint4*)(Bhp + 8) : z4;
    bl0 = bval ? *(const uint4*)(Blp) : z4;
    bl1 = bval ? *(const uint4*)(Blp + 8) : z4;

    for (int k0 = 0; k0 < K; k0 += 32) {
        // split current A tile (regs)
        unsigned hp[8], lp[8];
        #pragma unroll
        for (int j = 0; j < 8; j++) {
            float a0 = av[2 * j], a1 = av[2 * j + 1];
            unsigned u0 = __float_as_uint(a0), u1 = __float_as_uint(a1);
            unsigned h0 = u0 & 0xFFFF0000u, h1 = u1 & 0xFFFF0000u;
            float r0 = a0 - __uint_as_float(h0);
            float r1 = a1 - __uint_as_float(h1);
            hp[j] = (u0 >> 16) | h1;
            lp[j] = (__float_as_uint(r0) >> 16) | (__float_as_uint(r1) & 0xFFFF0000u);
        }
        __syncthreads();
        *(uint4*)&Ah[srow][sk]     = *(uint4*)&hp[0];
        *(uint4*)&Ah[srow][sk + 8] = *(uint4*)&hp[4];
        *(uint4*)&Al[srow][sk]     = *(uint4*)&lp[0];
        *(uint4*)&Al[srow][sk + 8] = *(uint4*)&lp[4];
        *(uint4*)&Bh[srow][sk]     = bh0;
        *(uint4*)&Bh[srow][sk + 8] = bh1;
        *(uint4*)&Bl[srow][sk]     = bl0;
        *(uint4*)&Bl[srow][sk + 8] = bl1;
        __syncthreads();
        // prefetch NEXT tile (no wait: consumed at next iteration's split)
        if (k0 + 32 < K) {
            #pragma unroll
            for (int i = 0; i < 4; i++)
                *(float4*)&av[4 * i] = *(const float4*)(Ap + k0 + 32 + 4 * i);
            bh0 = bval ? *(const uint4*)(Bhp + k0 + 32) : z4;
            bh1 = bval ? *(const uint4*)(Bhp + k0 + 40) : z4;
            bl0 = bval ? *(const uint4*)(Blp + k0 + 32) : z4;
            bl1 = bval ? *(const uint4*)(Blp + k0 + 40) : z4;
        }
        bf16x8 fah[4], fal[4], fbh[4], fbl[4];
        #pragma unroll
        for (int t = 0; t < 4; t++) {
            fah[t] = *(const bf16x8*)&Ah[wm + t * 16 + ln][quad * 8];
            fal[t] = *(const bf16x8*)&Al[wm + t * 16 + ln][quad * 8];
            fbh[t] = *(const bf16x8*)&Bh[wn + t * 16 + ln][quad * 8];
            fbl[t] = *(const bf16x8*)&Bl[wn + t * 16 + ln][quad * 8];
        }
        #pragma unroll
        for (int mt = 0; mt < 4; mt++)
            #pragma unroll
            for (int nt = 0; nt < 4; nt++) {
                acc[mt][nt] = __builtin_amdgcn_mfma_f32_16x16x32_bf16(fal[mt], fbh[nt], acc[mt][nt], 0, 0, 0);
                acc[mt][nt] = __builtin_amdgcn_mfma_f32_16x16x32_bf16(fah[mt], fbl[nt], acc[mt][nt], 0, 0, 0);
                acc[mt][nt] = __builtin_amdgcn_mfma_f32_16x16x32_bf16(fah[mt], fbh[nt], acc[mt][nt], 0, 0, 0);
            }
    }
    #pragma unroll
    for (int mt = 0; mt < 4; mt++)
        #pragma unroll
        for (int nt = 0; nt < 4; nt++) {
            int cn = n0 + wn + nt * 16 + ln;
            if (cn < N) {
                #pragma unroll
                for (int r = 0; r < 4; r++) {
                    int cm = m0 + wm + mt * 16 + quad * 4 + r;
                    C[(size_t)cm * N + cn] = acc[mt][nt][r];
                }
            }
        }
}

// ---------------- fallback GEMM: fp32 A and B, in-kernel split ----------------
__global__ __launch_bounds__(256, 2)
void k_gemm_mfma(const float* __restrict__ A, const float* __restrict__ B,
                 float* __restrict__ C, int M, int N, int K) {
    __shared__ u16 Ah[128][LDKP], Al[128][LDKP];
    __shared__ u16 Bh[128][LDKP], Bl[128][LDKP];
    int n0 = blockIdx.x * 128, m0 = blockIdx.y * 128;
    int tid = threadIdx.x;
    int srow = tid >> 1, sk = (tid & 1) * 16;
    int lane = tid & 63, wave = tid >> 6;
    int wm = (wave >> 1) * 64, wn = (wave & 1) * 64;
    int ln = lane & 15, quad = lane >> 4;
    f32x4 acc[4][4];
    #pragma unroll
    for (int i = 0; i < 4; i++)
        #pragma unroll
        for (int j = 0; j < 4; j++) acc[i][j] = (f32x4){0.f, 0.f, 0.f, 0.f};
    const float* Ap = A + (size_t)(m0 + srow) * K + sk;
    const float* Bp = B + (size_t)(n0 + srow) * K + sk;
    bool bval = (n0 + srow) < N;
    for (int k0 = 0; k0 < K; k0 += 32) {
        float av[16], bv[16];
        #pragma unroll
        for (int i = 0; i < 4; i++) {
            *(float4*)&av[4 * i] = *(const float4*)(Ap + k0 + 4 * i);
            *(float4*)&bv[4 * i] = bval ? *(const float4*)(Bp + k0 + 4 * i)
                                        : make_float4(0.f, 0.f, 0.f, 0.f);
        }
        __syncthreads();
        #pragma unroll
        for (int g = 0; g < 2; g++) {
            unsigned hiA[4], loA[4], hiB[4], loB[4];
            #pragma unroll
            for (int j = 0; j < 4; j++) {
                float a0 = av[8 * g + 2 * j], a1 = av[8 * g + 2 * j + 1];
                unsigned short h0 = f2bf(a0), h1 = f2bf(a1);
                unsigned short l0 = f2bf(a0 - bf2f(h0)), l1 = f2bf(a1 - bf2f(h1));
                hiA[j] = (unsigned)h0 | ((unsigned)h1 << 16);
                loA[j] = (unsigned)l0 | ((unsigned)l1 << 16);
                float b0 = bv[8 * g + 2 * j], b1 = bv[8 * g + 2 * j + 1];
                unsigned short g0 = f2bf(b0), g1 = f2bf(b1);
                unsigned short m0s = f2bf(b0 - bf2f(g0)), m1s = f2bf(b1 - bf2f(g1));
                hiB[j] = (unsigned)g0 | ((unsigned)g1 << 16);
                loB[j] = (unsigned)m0s | ((unsigned)m1s << 16);
            }
            *(uint4*)&Ah[srow][sk + 8 * g] = *(uint4*)hiA;
            *(uint4*)&Al[srow][sk + 8 * g] = *(uint4*)loA;
            *(uint4*)&Bh[srow][sk + 8 * g] = *(uint4*)hiB;
            *(uint4*)&Bl[srow][sk + 8 * g] = *(uint4*)loB;
        }
        __syncthreads();
        bf16x8 fah[4], fal[4], fbh[4], fbl[4];
        #pragma unroll
        for (int t = 0; t < 4; t++) {
            fah[t] = *(const bf16x8*)&Ah[wm + t * 16 + ln][quad * 8];
            fal[t] = *(const bf16x8*)&Al[wm + t * 16 + ln][quad * 8];
            fbh[t] = *(const bf16x8*)&Bh[wn + t * 16 + ln][quad * 8];
            fbl[t] = *(const bf16x8*)&Bl[wn + t * 16 + ln][quad * 8];
        }
        #pragma unroll
        for (int mt = 0; mt < 4; mt++)
            #pragma unroll
            for (int nt = 0; nt < 4; nt++) {
                acc[mt][nt] = __builtin_amdgcn_mfma_f32_16x16x32_bf16(fal[mt], fbh[nt], acc[mt][nt], 0, 0, 0);
                acc[mt][nt] = __builtin_amdgcn_mfma_f32_16x16x32_bf16(fah[mt], fbl[nt], acc[mt][nt], 0, 0, 0);
                acc[mt][nt] = __builtin_amdgcn_mfma_f32_16x16x32_bf16(fah[mt], fbh[nt], acc[mt][nt], 0, 0, 0);
            }
    }
    #pragma unroll
    for (int mt = 0; mt < 4; mt++)
        #pragma unroll
        for (int nt = 0; nt < 4; nt++) {
            int cn = n0 + wn + nt * 16 + ln;
            if (cn < N) {
                #pragma unroll
                for (int r = 0; r < 4; r++) {
                    int cm = m0 + wm + mt * 16 + quad * 4 + r;
                    C[(size_t)cm * N + cn] = acc[mt][nt][r];
                }
            }
        }
}

// ---------------- pack x / pack w ----------------
__global__ __launch_bounds__(256)
void k_pack_x(const float* __restrict__ x, float* __restrict__ xp) {
    size_t idx = (size_t)blockIdx.x * 256 + threadIdx.x;
    int k = (int)(idx & 63);
    size_t m = idx >> 6;
    xp[idx] = (k < D_IN) ? x[m * D_IN + k] : 0.f;
}
__global__ __launch_bounds__(256)
void k_pack_w(const float* __restrict__ w, float* __restrict__ wp) {
    int idx = blockIdx.x * 256 + threadIdx.x;
    int k = idx & 63, n = idx >> 6;
    wp[idx] = (k < D_IN) ? w[n * D_IN + k] : 0.f;
}

// ---------------- h = LN(pre + in_b) ----------------
__global__ __launch_bounds__(256)
void k_lnio(const float* __restrict__ pre, const float* __restrict__ bias,
            const float* __restrict__ gw, const float* __restrict__ gb,
            float* __restrict__ h) {
    int m = blockIdx.x, o = threadIdx.x;
    __shared__ float sred[8];
    float v = pre[(size_t)m * D_MODEL + o] + bias[o];
    float2 s = block_reduce2(v, v * v, sred);
    float mu = s.x * (1.f / D_MODEL);
    float var = s.y * (1.f / D_MODEL) - mu * mu;
    h[(size_t)m * D_MODEL + o] = (v - mu) * rsqrtf(var + EPS) * gw[o] + gb[o];
}

// ---------------- conv (causal depthwise k=4) + silu + dt ----------------
__global__ __launch_bounds__(256)
void k_conv(const float* __restrict__ xbc, const float* __restrict__ cw,
            const float* __restrict__ cb, const float* __restrict__ dtb,
            float* __restrict__ xs, float* __restrict__ Bm, float* __restrict__ Cm,
            float* __restrict__ dtv) {
    int m = blockIdx.x;
    int l = m & (LSEQ - 1);
    int tid = threadIdx.x;
    #pragma unroll
    for (int it = 0; it < 3; it++) {
        int c = tid + it * 256;
        float acc = cb[c];
        #pragma unroll
        for (int k = 0; k < DCONV; k++) {
            int lp = l - (DCONV - 1) + k;
            if (lp >= 0)
                acc = fmaf(cw[k * CONV_CH + c],
                           xbc[(size_t)(m - (DCONV - 1) + k) * XBCDT + c], acc);
        }
        float v = silu_f(acc);
        if (c < D_INNER) xs[(size_t)m * D_INNER + c] = v;
        else if (c < D_INNER + D_STATE) Bm[(size_t)m * D_STATE + (c - D_INNER)] = v;
        else Cm[(size_t)m * D_STATE + (c - D_INNER - D_STATE)] = v;
    }
    if (tid < NH) {
        float draw = xbc[(size_t)m * XBCDT + CONV_CH + tid] + dtb[tid];
        float dt = draw > 20.f ? draw : log1pf(expf(draw));
        dtv[m * NH + tid] = dt;
    }
}

// ---------------- Pass A: segment-local scan (round-9 proven) ----------------
__global__ __launch_bounds__(256, 4)
void k_scan_seg(const float* __restrict__ xs, const float* __restrict__ Bm,
                const float* __restrict__ Cm, const float* __restrict__ dtv,
                const float* __restrict__ Alog, const float* __restrict__ Dvec,
                float* __restrict__ y, float* __restrict__ F,
                float* __restrict__ cumdA) {
    int blk = blockIdx.x;
    int bh = blk >> 2;
    int seg = blk & (SSEG - 1);
    int b = bh >> 3, hh = bh & 7;
    int tid = threadIdx.x;
    int q = tid & 7;
    int pl = tid >> 3;
    int q2 = q >> 1;
    __shared__ __align__(16) float sBC[2 * CT * 128];
    __shared__ __align__(16) float sX[CT][HP];
    __shared__ float sdt[CT], sdA[CT], srdA[CT];
    float h0[16], h1[16];
    #pragma unroll
    for (int i = 0; i < 16; i++) { h0[i] = 0.f; h1[i] = 0.f; }
    float Dh = Dvec[hh];
    float Ahv = -expf(Alog[hh]);
    float c_run = 1.f;
    const size_t base = (size_t)b * LSEQ + (size_t)seg * TSEG;
    int col = tid & 127, half = tid >> 7;
    int sw = swz8(col);
    int xc = tid & 63, xh = tid >> 6;

    float rB[8], rC[8], rX[4], rdt = 0.f;
    #pragma unroll
    for (int u = 0; u < 8; u++) {
        size_t m = base + 2 * u + half;
        rB[u] = Bm[m * D_STATE + col];
        rC[u] = Cm[m * D_STATE + col];
    }
    #pragma unroll
    for (int u = 0; u < 4; u++)
        rX[u] = xs[(base + 4 * u + xh) * D_INNER + hh * HP + xc];
    if (tid < CT) rdt = dtv[(base + tid) * NH + hh];

    for (int c0 = 0; c0 < TSEG; c0 += CT) {
        #pragma unroll
        for (int u = 0; u < 8; u++) {
            int s = 2 * u + half;
            sBC[s * 128 + sw] = rB[u];
            sBC[(CT + s) * 128 + sw] = rC[u];
        }
        #pragma unroll
        for (int u = 0; u < 4; u++)
            sX[4 * u + xh][xc] = rX[u];
        if (tid < CT) {
            float e = fmaxf(rdt * Ahv, -37.f);
            sdt[tid] = rdt;
            sdA[tid] = expf(e);
            srdA[tid] = expf(-e);
        }
        __syncthreads();
        if (c0 + CT < TSEG) {
            size_t nb = base + c0 + CT;
            #pragma unroll
            for (int u = 0; u < 8; u++) {
                size_t m = nb + 2 * u + half;
                rB[u] = Bm[m * D_STATE + col];
                rC[u] = Cm[m * D_STATE + col];
            }
            #pragma unroll
            for (int u = 0; u < 4; u++)
                rX[u] = xs[(nb + 4 * u + xh) * D_INNER + hh * HP + xc];
            if (tid < CT) rdt = dtv[(nb + tid) * NH + hh];
        }
        if (tid == 0) {
            float cg = c_run;
            for (int s = 0; s < CT; s++) {
                cg *= sdA[s];
                cumdA[(base + c0 + s) * NH + hh] = cg;
            }
            c_run = cg;
        }
        float cc = 1.f, rc = 1.f;
        #pragma unroll
        for (int s = 0; s < CT; s++) {
            float dAl = sdA[s], dtl = sdt[s];
            float ccn = cc * dAl;
            if (ccn < 1e-18f) {
                #pragma unroll
                for (int i = 0; i < 16; i++) { h0[i] *= cc; h1[i] *= cc; }
                rc = srdA[s];
                ccn = dAl;
            } else {
                rc *= srdA[s];
            }
            cc = ccn;
            float xv0 = sX[s][pl];
            float xv1 = sX[s][pl + 32];
            float dr = dtl * rc;
            float t0 = dr * xv0, t1 = dr * xv1;
            float ya0 = 0.f, yb0 = 0.f, ya1 = 0.f, yb1 = 0.f;
            #pragma unroll
            for (int i = 0; i < 4; i++) {
                int off = (q << 4) + (((i + q2) & 3) << 2);
                float4 bv = *(const float4*)&sBC[s * 128 + off];
                float4 cv = *(const float4*)&sBC[(CT + s) * 128 + off];
                h0[4*i+0] = fmaf(t0, bv.x, h0[4*i+0]); ya0 = fmaf(h0[4*i+0], cv.x, ya0);
                h0[4*i+1] = fmaf(t0, bv.y, h0[4*i+1]); yb0 = fmaf(h0[4*i+1], cv.y, yb0);
                h0[4*i+2] = fmaf(t0, bv.z, h0[4*i+2]); ya0 = fmaf(h0[4*i+2], cv.z, ya0);
                h0[4*i+3] = fmaf(t0, bv.w, h0[4*i+3]); yb0 = fmaf(h0[4*i+3], cv.w, yb0);
                h1[4*i+0] = fmaf(t1, bv.x, h1[4*i+0]); ya1 = fmaf(h1[4*i+0], cv.x, ya1);
                h1[4*i+1] = fmaf(t1, bv.y, h1[4*i+1]); yb1 = fmaf(h1[4*i+1], cv.y, yb1);
                h1[4*i+2] = fmaf(t1, bv.z, h1[4*i+2]); ya1 = fmaf(h1[4*i+2], cv.z, ya1);
                h1[4*i+3] = fmaf(t1, bv.w, h1[4*i+3]); yb1 = fmaf(h1[4*i+3], cv.w, yb1);
            }
            float yp0 = ya0 + yb0;
            float yp1 = ya1 + yb1;
            yp0 += __shfl_xor(yp0, 1);  yp1 += __shfl_xor(yp1, 1);
            yp0 += __shfl_xor(yp0, 2);  yp1 += __shfl_xor(yp1, 2);
            yp0 += __shfl_xor(yp0, 4);  yp1 += __shfl_xor(yp1, 4);
            if (q == 0) {
                size_t row = (base + c0 + s) * D_INNER + hh * HP;
                y[row + pl]      = fmaf(Dh, xv0, cc * yp0);
                y[row + pl + 32] = fmaf(Dh, xv1, cc * yp1);
            }
            if ((s & (RS - 1)) == RS - 1) {
                #pragma unroll
                for (int i = 0; i < 16; i++) { h0[i] *= cc; h1[i] *= cc; }
                cc = 1.f; rc = 1.f;
            }
        }
        __syncthreads();
    }
    if (seg < SSEG - 1) {
        float* F0 = F + (((size_t)bh * (SSEG - 1) + seg) * HP + pl) * D_STATE + (q << 4);
        float* F1 = F + (((size_t)bh * (SSEG - 1) + seg) * HP + pl + 32) * D_STATE + (q << 4);
        #pragma unroll
        for (int i = 0; i < 4; i++) {
            *(float4*)(F0 + 4 * i) = make_float4(h0[4*i], h0[4*i+1], h0[4*i+2], h0[4*i+3]);
            *(float4*)(F1 + 4 * i) = make_float4(h1[4*i], h1[4*i+1], h1[4*i+2], h1[4*i+3]);
        }
    }
}

// ---------------- Pass C (fused combine), round-9 proven ----------------
__global__ __launch_bounds__(256, 4)
void k_seg_fix(const float* __restrict__ Cm, const float* __restrict__ cumdA,
               const float* __restrict__ F, float* __restrict__ y) {
    int blk = blockIdx.x;
    int bh = blk / (SSEG - 1);
    int seg = blk - bh * (SSEG - 1) + 1;
    int b = bh >> 3, hh = bh & 7;
    int tid = threadIdx.x;
    int q = tid & 7;
    int pl = tid >> 3;
    int q2 = q >> 1;
    float g0[16], g1[16];
    #pragma unroll
    for (int i = 0; i < 16; i++) { g0[i] = 0.f; g1[i] = 0.f; }
    for (int s = 0; s < seg; s++) {
        float P = cumdA[((size_t)b * LSEQ + (size_t)(s + 1) * TSEG - 1) * NH + hh];
        const float* F0 = F + (((size_t)bh * (SSEG - 1) + s) * HP + pl) * D_STATE + (q << 4);
        const float* F1 = F + (((size_t)bh * (SSEG - 1) + s) * HP + pl + 32) * D_STATE + (q << 4);
        #pragma unroll
        for (int i = 0; i < 4; i++) {
            float4 f0 = *(const float4*)(F0 + 4 * i);
            float4 f1 = *(const float4*)(F1 + 4 * i);
            g0[4*i+0] = fmaf(g0[4*i+0], P, f0.x);
            g0[4*i+1] = fmaf(g0[4*i+1], P, f0.y);
            g0[4*i+2] = fmaf(g0[4*i+2], P, f0.z);
            g0[4*i+3] = fmaf(g0[4*i+3], P, f0.w);
            g1[4*i+0] = fmaf(g1[4*i+0], P, f1.x);
            g1[4*i+1] = fmaf(g1[4*i+1], P, f1.y);
            g1[4*i+2] = fmaf(g1[4*i+2], P, f1.z);
            g1[4*i+3] = fmaf(g1[4*i+3], P, f1.w);
        }
    }
    __shared__ __align__(16) float sC[CT * 128];
    __shared__ float scd[CT];
    const size_t base = (size_t)b * LSEQ + (size_t)seg * TSEG;
    int col = tid & 127, half = tid >> 7;
    int sw = swz8(col);
    float rC[8], rcd = 0.f;
    #pragma unroll
    for (int u = 0; u < 8; u++)
        rC[u] = Cm[(base + 2 * u + half) * D_STATE + col];
    if (tid < CT) rcd = cumdA[(base + tid) * NH + hh];

    for (int c0 = 0; c0 < TSEG; c0 += CT) {
        #pragma unroll
        for (int u = 0; u < 8; u++)
            sC[(2 * u + half) * 128 + sw] = rC[u];
        if (tid < CT) scd[tid] = rcd;
        __syncthreads();
        if (c0 + CT < TSEG) {
            size_t nb = base + c0 + CT;
            #pragma unroll
            for (int u = 0; u < 8; u++)
                rC[u] = Cm[(nb + 2 * u + half) * D_STATE + col];
            if (tid < CT) rcd = cumdA[(nb + tid) * NH + hh];
        }
        #pragma unroll 1
        for (int s = 0; s < CT; s++) {
            float ya0 = 0.f, yb0 = 0.f, ya1 = 0.f, yb1 = 0.f;
            #pragma unroll
            for (int i = 0; i < 4; i++) {
                int off = (q << 4) + (((i + q2) & 3) << 2);
                float4 cv = *(const float4*)&sC[s * 128 + off];
                ya0 = fmaf(g0[4*i+0], cv.x, ya0);
                yb0 = fmaf(g0[4*i+1], cv.y, yb0);
                ya0 = fmaf(g0[4*i+2], cv.z, ya0);
                yb0 = fmaf(g0[4*i+3], cv.w, yb0);
                ya1 = fmaf(g1[4*i+0], cv.x, ya1);
                yb1 = fmaf(g1[4*i+1], cv.y, yb1);
                ya1 = fmaf(g1[4*i+2], cv.z, ya1);
                yb1 = fmaf(g1[4*i+3], cv.w, yb1);
            }
            float yp0 = ya0 + yb0;
            float yp1 = ya1 + yb1;
            yp0 += __shfl_xor(yp0, 1);  yp1 += __shfl_xor(yp1, 1);
            yp0 += __shfl_xor(yp0, 2);  yp1 += __shfl_xor(yp1, 2);
            yp0 += __shfl_xor(yp0, 4);  yp1 += __shfl_xor(yp1, 4);
            if (q == 0) {
                size_t row = (base + c0 + s) * D_INNER + hh * HP;
                y[row + pl]      += scd[s] * yp0;
                y[row + pl + 32] += scd[s] * yp1;
            }
        }
        __syncthreads();
    }
}

// ---------------- gated RMSNorm (in-place on y) ----------------
__global__ __launch_bounds__(256)
void k_gate(float* __restrict__ y, const float* __restrict__ zbuf,
            const float* __restrict__ nw) {
    int m = blockIdx.x, tid = threadIdx.x;
    __shared__ float sred[8];
    float g[2];
    #pragma unroll
    for (int j = 0; j < 2; j++) {
        int d = tid + j * 256;
        float z = zbuf[(size_t)m * D_INNER + d];
        g[j] = y[(size_t)m * D_INNER + d] * silu_f(z);
    }
    float2 s = block_reduce2(g[0] * g[0] + g[1] * g[1], 0.f, sred);
    float r = rsqrtf(s.x * (1.f / D_INNER) + EPS);
    #pragma unroll
    for (int j = 0; j < 2; j++) {
        int d = tid + j * 256;
        y[(size_t)m * D_INNER + d] = g[j] * r * nw[d];
    }
}

// ---------------- h = LN(mo + h) ----------------
__global__ __launch_bounds__(256)
void k_addln(const float* __restrict__ mo, float* __restrict__ h,
             const float* __restrict__ w, const float* __restrict__ bias) {
    int m = blockIdx.x, o = threadIdx.x;
    __shared__ float sred[8];
    float v = mo[(size_t)m * D_MODEL + o] + h[(size_t)m * D_MODEL + o];
    float2 s = block_reduce2(v, v * v, sred);
    float mu = s.x * (1.f / D_MODEL);
    float var = s.y * (1.f / D_MODEL) - mu * mu;
    h[(size_t)m * D_MODEL + o] = (v - mu) * rsqrtf(var + EPS) * w[o] + bias[o];
}

// ---------------- pooled partial sums: 16 chunks of 64 tokens per batch ----------
__global__ __launch_bounds__(256)
void k_pool_part(const float* __restrict__ h, const int* __restrict__ len,
                 float* __restrict__ part) {
    int blk = blockIdx.x;
    int b = blk >> 4, ch = blk & 15;
    int d = threadIdx.x;
    int Lb = len[b];
    int l0 = ch * 64;
    int le = min(l0 + 64, Lb);
    float acc = 0.f;
    for (int l = l0; l < le; l++) acc += h[((size_t)b * LSEQ + l) * D_MODEL + d];
    part[(size_t)blk * D_MODEL + d] = acc;
}

// ---------------- final head: pooled mean + 14-way linear ----------------
__global__ __launch_bounds__(256)
void k_head(const float* __restrict__ part, const int* __restrict__ len,
            const float* __restrict__ hw, const float* __restrict__ hb,
            float* __restrict__ out) {
    int b = blockIdx.x, d = threadIdx.x;
    __shared__ float sp[D_MODEL];
    float a = 0.f;
    #pragma unroll
    for (int c = 0; c < 16; c++) a += part[(size_t)(b * 16 + c) * D_MODEL + d];
    sp[d] = a / (float)len[b];
    __syncthreads();
    if (d < N_CLS) {
        float o = hb[d];
        const float* wr = hw + (size_t)d * D_MODEL;
        #pragma unroll 8
        for (int k = 0; k < D_MODEL; k++) o = fmaf(sp[k], wr[k], o);
        out[b * N_CLS + d] = o;
    }
}

extern "C" void kernel_launch(void* const* d_in, const int* in_sizes, int n_in,
                              void* d_out, int out_size, void* d_ws, size_t ws_size,
                              hipStream_t stream) {
    const float* x      = (const float*)d_in[0];
    const float* in_w   = (const float*)d_in[1];
    const float* in_b   = (const float*)d_in[2];
    const float* lnin_w = (const float*)d_in[3];
    const float* lnin_b = (const float*)d_in[4];
    const float* inproj = (const float*)d_in[5];
    const float* conv_w = (const float*)d_in[6];
    const float* conv_b = (const float*)d_in[7];
    const float* dt_bias= (const float*)d_in[8];
    const float* A_log  = (const float*)d_in[9];
    const float* Dv     = (const float*)d_in[10];
    const float* norm_w = (const float*)d_in[11];
    const float* outp_w = (const float*)d_in[12];
    const float* ln_w   = (const float*)d_in[13];
    const float* ln_b   = (const float*)d_in[14];
    const float* head_w = (const float*)d_in[15];
    const float* head_b = (const float*)d_in[16];
    const int*   lengths= (const int*)d_in[17];
    float* out = (float*)d_out;

    float* ws    = (float*)d_ws;
    float* h     = ws;
    float* buf1  = h    + (size_t)NTOK * D_MODEL;
    float* xs    = buf1 + (size_t)NTOK * XBCDT;
    float* Bm    = xs   + (size_t)NTOK * D_INNER;
    float* Cm    = Bm   + (size_t)NTOK * D_STATE;
    float* dtv   = Cm   + (size_t)NTOK * D_STATE;
    float* cumdA = dtv  + (size_t)NTOK * NH;
    float* zbuf  = buf1;
    float* F     = buf1 + (size_t)NTOK * D_INNER;
    float* mo    = Bm;
    float* xp    = buf1;
    float* pre   = buf1 + (size_t)NTOK * 64;
    float* poolp = buf1;
    unsigned short* WP = (unsigned short*)(ws + WS_BASE);
    bool use_pk = (ws_size >= WS_NEED);

    dim3 gIO(D_MODEL / 128, NTOK / 128);
    dim3 g1a((XBCDT + 127) / 128, NTOK / 128);
    dim3 g1b(D_INNER / 128, NTOK / 128);
    int gScan = BSZ * NH * SSEG;
    int gFix  = BSZ * NH * (SSEG - 1);

    if (use_pk) {
        k_pack_weights<<<TOTPK / 256, 256, 0, stream>>>(in_w, inproj, outp_w, WP);
        k_pack_x<<<NTOK * 64 / 256, 256, 0, stream>>>(x, xp);
        k_gemm_as<<<gIO, 256, 0, stream>>>(xp, WP + IN_HI, WP + IN_LO, pre,
                                           NTOK, D_MODEL, 64);
        k_lnio<<<NTOK, 256, 0, stream>>>(pre, in_b, lnin_w, lnin_b, h);
        for (int i = 0; i < NL; i++) {
            const u16* iph = WP + IP_HI + (size_t)i * PROJ * D_MODEL;
            const u16* ipl = WP + IP_LO + (size_t)i * PROJ * D_MODEL;
            k_gemm_as<<<g1a, 256, 0, stream>>>(h, iph + (size_t)D_INNER * D_MODEL,
                                               ipl + (size_t)D_INNER * D_MODEL,
                                               buf1, NTOK, XBCDT, D_MODEL);
            k_conv<<<NTOK, 256, 0, stream>>>(buf1, conv_w + i * DCONV * CONV_CH,
                                             conv_b + i * CONV_CH, dt_bias + i * NH,
                                             xs, Bm, Cm, dtv);
            k_gemm_as<<<g1b, 256, 0, stream>>>(h, iph, ipl, zbuf, NTOK, D_INNER, D_MODEL);
            k_scan_seg<<<gScan, 256, 0, stream>>>(xs, Bm, Cm, dtv,
                                                  A_log + i * NH, Dv + i * NH,
                                                  xs, F, cumdA);
            k_seg_fix<<<gFix, 256, 0, stream>>>(Cm, cumdA, F, xs);
            k_gate<<<NTOK, 256, 0, stream>>>(xs, zbuf, norm_w + i * D_INNER);
            k_gemm_as<<<gIO, 256, 0, stream>>>(xs, WP + OP_HI + (size_t)i * D_MODEL * D_INNER,
                                               WP + OP_LO + (size_t)i * D_MODEL * D_INNER,
                                               mo, NTOK, D_MODEL, D_INNER);
            k_addln<<<NTOK, 256, 0, stream>>>(mo, h, ln_w + i * D_MODEL, ln_b + i * D_MODEL);
        }
    } else {
        float* wp = Bm;
        k_pack_x<<<NTOK * 64 / 256, 256, 0, stream>>>(x, xp);
        k_pack_w<<<64, 256, 0, stream>>>(in_w, wp);
        k_gemm_mfma<<<gIO, 256, 0, stream>>>(xp, wp, pre, NTOK, D_MODEL, 64);
        k_lnio<<<NTOK, 256, 0, stream>>>(pre, in_b, lnin_w, lnin_b, h);
        for (int i = 0; i < NL; i++) {
            const float* W = inproj + (size_t)i * PROJ * D_MODEL;
            k_gemm_mfma<<<g1a, 256, 0, stream>>>(h, W + (size_t)D_INNER * D_MODEL,
                                                 buf1, NTOK, XBCDT, D_MODEL);
            k_conv<<<NTOK, 256, 0, stream>>>(buf1, conv_w + i * DCONV * CONV_CH,
                                             conv_b + i * CONV_CH, dt_bias + i * NH,
                                             xs, Bm, Cm, dtv);
            k_gemm_mfma<<<g1b, 256, 0, stream>>>(h, W, zbuf, NTOK, D_INNER, D_MODEL);
            k_scan_seg<<<gScan, 256, 0, stream>>>(xs, Bm, Cm, dtv,
                                                  A_log + i * NH, Dv + i * NH,
                                                  xs, F, cumdA);
            k_seg_fix<<<gFix, 256, 0, stream>>>(Cm, cumdA, F, xs);
            k_gate<<<NTOK, 256, 0, stream>>>(xs, zbuf, norm_w + i * D_INNER);
            k_gemm_mfma<<<gIO, 256, 0, stream>>>(xs, outp_w + (size_t)i * D_MODEL * D_INNER,
                                                 mo, NTOK, D_MODEL, D_INNER);
            k_addln<<<NTOK, 256, 0, stream>>>(mo, h, ln_w + i * D_MODEL, ln_b + i * D_MODEL);
        }
    }

    k_pool_part<<<BSZ * 16, 256, 0, stream>>>(h, lengths, poolp);
    k_head<<<BSZ, 256, 0, stream>>>(poolp, lengths, head_w, head_b, out);
}

// Round 13
// 2589.941 us; speedup vs baseline: 1.0535x; 1.0414x over previous
//
#include <hip/hip_runtime.h>
#include <math.h>

#define D_IN 63
#define D_MODEL 256
#define N_CLS 14
#define NL 4
#define D_INNER 512
#define D_STATE 128
#define NH 8
#define HP 64
#define DCONV 4
#define CONV_CH 768
#define PROJ 1288
#define XBCDT 776
#define EPS 1e-5f
#define BSZ 32
#define LSEQ 1024
#define NTOK (BSZ*LSEQ)

#define SSEG 4
#define TSEG (LSEQ/SSEG)
#define CT 16
#define RS 8

// weight-pack region (ushort offsets)
#define S_IN   16384
#define S_IP   1318912
#define S_OP   524288
#define IN_HI  0
#define IN_LO  16384
#define IP_HI  32768
#define IP_LO  (32768 + S_IP)
#define OP_HI  (32768 + 2*S_IP)
#define OP_LO  (OP_HI + S_OP)
#define TOTPK  (S_IN + S_IP + S_OP)
#define WS_BASE ((size_t)NTOK * 1816)
#define WS_NEED ((WS_BASE + (size_t)TOTPK) * 4)

typedef __attribute__((ext_vector_type(8))) short bf16x8;
typedef __attribute__((ext_vector_type(4))) float f32x4;
typedef unsigned short u16;

__device__ __forceinline__ float silu_f(float x) { return x / (1.f + expf(-x)); }

__device__ __forceinline__ unsigned short f2bf(float x) {
    union { float f; unsigned u; } v; v.f = x;
    unsigned r = v.u + 0x7FFFu + ((v.u >> 16) & 1u);
    return (unsigned short)(r >> 16);
}
__device__ __forceinline__ float bf2f(unsigned short h) {
    union { float f; unsigned u; } v; v.u = ((unsigned)h) << 16; return v.f;
}

// swizzle for 8 groups of 16 values (proven 0-conflict)
__device__ __forceinline__ int swz8(int n) {
    int g = n >> 4, j = (n >> 2) & 3, e = n & 3;
    return (g << 4) + (((j + (g >> 1)) & 3) << 2) + e;
}

__device__ __forceinline__ float2 block_reduce2(float a, float b, float* sred) {
    #pragma unroll
    for (int off = 32; off >= 1; off >>= 1) {
        a += __shfl_xor(a, off);
        b += __shfl_xor(b, off);
    }
    int wid = threadIdx.x >> 6, lane = threadIdx.x & 63;
    if (lane == 0) { sred[wid * 2] = a; sred[wid * 2 + 1] = b; }
    __syncthreads();
    a = sred[0] + sred[2] + sred[4] + sred[6];
    b = sred[1] + sred[3] + sred[5] + sred[7];
    __syncthreads();
    return make_float2(a, b);
}

// ---------------- pack all weights to bf16 hi/lo planes ----------------
__global__ __launch_bounds__(256)
void k_pack_weights(const float* __restrict__ in_w, const float* __restrict__ inproj,
                    const float* __restrict__ outp, u16* __restrict__ WP) {
    int idx = blockIdx.x * 256 + threadIdx.x;
    float v; int hi_off, lo_off;
    if (idx < S_IN) {
        int n = idx >> 6, k = idx & 63;
        v = (k < D_IN) ? in_w[n * D_IN + k] : 0.f;
        hi_off = IN_HI + idx; lo_off = IN_LO + idx;
    } else if (idx < S_IN + S_IP) {
        int j = idx - S_IN;
        v = inproj[j];
        hi_off = IP_HI + j; lo_off = IP_LO + j;
    } else {
        int j = idx - S_IN - S_IP;
        v = outp[j];
        hi_off = OP_HI + j; lo_off = OP_LO + j;
    }
    unsigned short h = f2bf(v);
    unsigned short l = f2bf(v - bf2f(h));
    WP[hi_off] = h; WP[lo_off] = l;
}

// ---------------- MFMA GEMM, A fp32 (in-kernel trunc split), B pre-packed ----------
#define LDKP 40
__global__ __launch_bounds__(256, 2)
void k_gemm_as(const float* __restrict__ A, const u16* __restrict__ Bhg,
               const u16* __restrict__ Blg, float* __restrict__ C,
               int M, int N, int K) {
    __shared__ u16 Ah[128][LDKP], Al[128][LDKP];
    __shared__ u16 Bh[128][LDKP], Bl[128][LDKP];
    int n0 = blockIdx.x * 128, m0 = blockIdx.y * 128;
    int tid = threadIdx.x;
    int srow = tid >> 1, sk = (tid & 1) * 16;
    int lane = tid & 63, wave = tid >> 6;
    int wm = (wave >> 1) * 64, wn = (wave & 1) * 64;
    int ln = lane & 15, quad = lane >> 4;
    f32x4 acc[4][4];
    #pragma unroll
    for (int i = 0; i < 4; i++)
        #pragma unroll
        for (int j = 0; j < 4; j++) acc[i][j] = (f32x4){0.f, 0.f, 0.f, 0.f};
    const float* Ap = A + (size_t)(m0 + srow) * K + sk;
    const u16* Bhp = Bhg + (size_t)(n0 + srow) * K + sk;
    const u16* Blp = Blg + (size_t)(n0 + srow) * K + sk;
    bool bval = (n0 + srow) < N;
    uint4 z4 = make_uint4(0u, 0u, 0u, 0u);
    for (int k0 = 0; k0 < K; k0 += 32) {
        float av[16];
        #pragma unroll
        for (int i = 0; i < 4; i++)
            *(float4*)&av[4 * i] = *(const float4*)(Ap + k0 + 4 * i);
        uint4 bh0 = bval ? *(const uint4*)(Bhp + k0) : z4;
        uint4 bh1 = bval ? *(const uint4*)(Bhp + k0 + 8) : z4;
        uint4 bl0 = bval ? *(const uint4*)(Blp + k0) : z4;
        uint4 bl1 = bval ? *(const uint4*)(Blp + k0 + 8) : z4;
        unsigned hp[8], lp[8];
        #pragma unroll
        for (int j = 0; j < 8; j++) {
            float a0 = av[2 * j], a1 = av[2 * j + 1];
            unsigned u0 = __float_as_uint(a0), u1 = __float_as_uint(a1);
            unsigned h0 = u0 & 0xFFFF0000u, h1 = u1 & 0xFFFF0000u;
            float r0 = a0 - __uint_as_float(h0);
            float r1 = a1 - __uint_as_float(h1);
            hp[j] = (u0 >> 16) | h1;
            lp[j] = (__float_as_uint(r0) >> 16) | (__float_as_uint(r1) & 0xFFFF0000u);
        }
        __syncthreads();
        *(uint4*)&Ah[srow][sk]     = *(uint4*)&hp[0];
        *(uint4*)&Ah[srow][sk + 8] = *(uint4*)&hp[4];
        *(uint4*)&Al[srow][sk]     = *(uint4*)&lp[0];
        *(uint4*)&Al[srow][sk + 8] = *(uint4*)&lp[4];
        *(uint4*)&Bh[srow][sk]     = bh0;
        *(uint4*)&Bh[srow][sk + 8] = bh1;
        *(uint4*)&Bl[srow][sk]     = bl0;
        *(uint4*)&Bl[srow][sk + 8] = bl1;
        __syncthreads();
        bf16x8 fah[4], fal[4], fbh[4], fbl[4];
        #pragma unroll
        for (int t = 0; t < 4; t++) {
            fah[t] = *(const bf16x8*)&Ah[wm + t * 16 + ln][quad * 8];
            fal[t] = *(const bf16x8*)&Al[wm + t * 16 + ln][quad * 8];
            fbh[t] = *(const bf16x8*)&Bh[wn + t * 16 + ln][quad * 8];
            fbl[t] = *(const bf16x8*)&Bl[wn + t * 16 + ln][quad * 8];
        }
        #pragma unroll
        for (int mt = 0; mt < 4; mt++)
            #pragma unroll
            for (int nt = 0; nt < 4; nt++) {
                acc[mt][nt] = __builtin_amdgcn_mfma_f32_16x16x32_bf16(fal[mt], fbh[nt], acc[mt][nt], 0, 0, 0);
                acc[mt][nt] = __builtin_amdgcn_mfma_f32_16x16x32_bf16(fah[mt], fbl[nt], acc[mt][nt], 0, 0, 0);
                acc[mt][nt] = __builtin_amdgcn_mfma_f32_16x16x32_bf16(fah[mt], fbh[nt], acc[mt][nt], 0, 0, 0);
            }
    }
    #pragma unroll
    for (int mt = 0; mt < 4; mt++)
        #pragma unroll
        for (int nt = 0; nt < 4; nt++) {
            int cn = n0 + wn + nt * 16 + ln;
            if (cn < N) {
                #pragma unroll
                for (int r = 0; r < 4; r++) {
                    int cm = m0 + wm + mt * 16 + quad * 4 + r;
                    C[(size_t)cm * N + cn] = acc[mt][nt][r];
                }
            }
        }
}

// ---------------- fallback GEMM: fp32 A and B, in-kernel split ----------------
__global__ __launch_bounds__(256, 2)
void k_gemm_mfma(const float* __restrict__ A, const float* __restrict__ B,
                 float* __restrict__ C, int M, int N, int K) {
    __shared__ u16 Ah[128][LDKP], Al[128][LDKP];
    __shared__ u16 Bh[128][LDKP], Bl[128][LDKP];
    int n0 = blockIdx.x * 128, m0 = blockIdx.y * 128;
    int tid = threadIdx.x;
    int srow = tid >> 1, sk = (tid & 1) * 16;
    int lane = tid & 63, wave = tid >> 6;
    int wm = (wave >> 1) * 64, wn = (wave & 1) * 64;
    int ln = lane & 15, quad = lane >> 4;
    f32x4 acc[4][4];
    #pragma unroll
    for (int i = 0; i < 4; i++)
        #pragma unroll
        for (int j = 0; j < 4; j++) acc[i][j] = (f32x4){0.f, 0.f, 0.f, 0.f};
    const float* Ap = A + (size_t)(m0 + srow) * K + sk;
    const float* Bp = B + (size_t)(n0 + srow) * K + sk;
    bool bval = (n0 + srow) < N;
    for (int k0 = 0; k0 < K; k0 += 32) {
        float av[16], bv[16];
        #pragma unroll
        for (int i = 0; i < 4; i++) {
            *(float4*)&av[4 * i] = *(const float4*)(Ap + k0 + 4 * i);
            *(float4*)&bv[4 * i] = bval ? *(const float4*)(Bp + k0 + 4 * i)
                                        : make_float4(0.f, 0.f, 0.f, 0.f);
        }
        __syncthreads();
        #pragma unroll
        for (int g = 0; g < 2; g++) {
            unsigned hiA[4], loA[4], hiB[4], loB[4];
            #pragma unroll
            for (int j = 0; j < 4; j++) {
                float a0 = av[8 * g + 2 * j], a1 = av[8 * g + 2 * j + 1];
                unsigned short h0 = f2bf(a0), h1 = f2bf(a1);
                unsigned short l0 = f2bf(a0 - bf2f(h0)), l1 = f2bf(a1 - bf2f(h1));
                hiA[j] = (unsigned)h0 | ((unsigned)h1 << 16);
                loA[j] = (unsigned)l0 | ((unsigned)l1 << 16);
                float b0 = bv[8 * g + 2 * j], b1 = bv[8 * g + 2 * j + 1];
                unsigned short g0 = f2bf(b0), g1 = f2bf(b1);
                unsigned short m0s = f2bf(b0 - bf2f(g0)), m1s = f2bf(b1 - bf2f(g1));
                hiB[j] = (unsigned)g0 | ((unsigned)g1 << 16);
                loB[j] = (unsigned)m0s | ((unsigned)m1s << 16);
            }
            *(uint4*)&Ah[srow][sk + 8 * g] = *(uint4*)hiA;
            *(uint4*)&Al[srow][sk + 8 * g] = *(uint4*)loA;
            *(uint4*)&Bh[srow][sk + 8 * g] = *(uint4*)hiB;
            *(uint4*)&Bl[srow][sk + 8 * g] = *(uint4*)loB;
        }
        __syncthreads();
        bf16x8 fah[4], fal[4], fbh[4], fbl[4];
        #pragma unroll
        for (int t = 0; t < 4; t++) {
            fah[t] = *(const bf16x8*)&Ah[wm + t * 16 + ln][quad * 8];
            fal[t] = *(const bf16x8*)&Al[wm + t * 16 + ln][quad * 8];
            fbh[t] = *(const bf16x8*)&Bh[wn + t * 16 + ln][quad * 8];
            fbl[t] = *(const bf16x8*)&Bl[wn + t * 16 + ln][quad * 8];
        }
        #pragma unroll
        for (int mt = 0; mt < 4; mt++)
            #pragma unroll
            for (int nt = 0; nt < 4; nt++) {
                acc[mt][nt] = __builtin_amdgcn_mfma_f32_16x16x32_bf16(fal[mt], fbh[nt], acc[mt][nt], 0, 0, 0);
                acc[mt][nt] = __builtin_amdgcn_mfma_f32_16x16x32_bf16(fah[mt], fbl[nt], acc[mt][nt], 0, 0, 0);
                acc[mt][nt] = __builtin_amdgcn_mfma_f32_16x16x32_bf16(fah[mt], fbh[nt], acc[mt][nt], 0, 0, 0);
            }
    }
    #pragma unroll
    for (int mt = 0; mt < 4; mt++)
        #pragma unroll
        for (int nt = 0; nt < 4; nt++) {
            int cn = n0 + wn + nt * 16 + ln;
            if (cn < N) {
                #pragma unroll
                for (int r = 0; r < 4; r++) {
                    int cm = m0 + wm + mt * 16 + quad * 4 + r;
                    C[(size_t)cm * N + cn] = acc[mt][nt][r];
                }
            }
        }
}

// ---------------- pack x / pack w ----------------
__global__ __launch_bounds__(256)
void k_pack_x(const float* __restrict__ x, float* __restrict__ xp) {
    size_t idx = (size_t)blockIdx.x * 256 + threadIdx.x;
    int k = (int)(idx & 63);
    size_t m = idx >> 6;
    xp[idx] = (k < D_IN) ? x[m * D_IN + k] : 0.f;
}
__global__ __launch_bounds__(256)
void k_pack_w(const float* __restrict__ w, float* __restrict__ wp) {
    int idx = blockIdx.x * 256 + threadIdx.x;
    int k = idx & 63, n = idx >> 6;
    wp[idx] = (k < D_IN) ? w[n * D_IN + k] : 0.f;
}

// ---------------- h = LN(pre + in_b) ----------------
__global__ __launch_bounds__(256)
void k_lnio(const float* __restrict__ pre, const float* __restrict__ bias,
            const float* __restrict__ gw, const float* __restrict__ gb,
            float* __restrict__ h) {
    int m = blockIdx.x, o = threadIdx.x;
    __shared__ float sred[8];
    float v = pre[(size_t)m * D_MODEL + o] + bias[o];
    float2 s = block_reduce2(v, v * v, sred);
    float mu = s.x * (1.f / D_MODEL);
    float var = s.y * (1.f / D_MODEL) - mu * mu;
    h[(size_t)m * D_MODEL + o] = (v - mu) * rsqrtf(var + EPS) * gw[o] + gb[o];
}

// ---------------- conv (causal depthwise k=4) + silu + dt ----------------
__global__ __launch_bounds__(256)
void k_conv(const float* __restrict__ xbc, const float* __restrict__ cw,
            const float* __restrict__ cb, const float* __restrict__ dtb,
            float* __restrict__ xs, float* __restrict__ Bm, float* __restrict__ Cm,
            float* __restrict__ dtv) {
    int m = blockIdx.x;
    int l = m & (LSEQ - 1);
    int tid = threadIdx.x;
    #pragma unroll
    for (int it = 0; it < 3; it++) {
        int c = tid + it * 256;
        float acc = cb[c];
        #pragma unroll
        for (int k = 0; k < DCONV; k++) {
            int lp = l - (DCONV - 1) + k;
            if (lp >= 0)
                acc = fmaf(cw[k * CONV_CH + c],
                           xbc[(size_t)(m - (DCONV - 1) + k) * XBCDT + c], acc);
        }
        float v = silu_f(acc);
        if (c < D_INNER) xs[(size_t)m * D_INNER + c] = v;
        else if (c < D_INNER + D_STATE) Bm[(size_t)m * D_STATE + (c - D_INNER)] = v;
        else Cm[(size_t)m * D_STATE + (c - D_INNER - D_STATE)] = v;
    }
    if (tid < NH) {
        float draw = xbc[(size_t)m * XBCDT + CONV_CH + tid] + dtb[tid];
        float dt = draw > 20.f ? draw : log1pf(expf(draw));
        dtv[m * NH + tid] = dt;
    }
}

// ---------------- Pass A: segment-local scan, 2p x 16n, staged-prefetch ----------
__global__ __launch_bounds__(256, 4)
void k_scan_seg(const float* __restrict__ xs, const float* __restrict__ Bm,
                const float* __restrict__ Cm, const float* __restrict__ dtv,
                const float* __restrict__ Alog, const float* __restrict__ Dvec,
                float* __restrict__ y, float* __restrict__ F,
                float* __restrict__ cumdA) {
    int blk = blockIdx.x;
    int bh = blk >> 2;
    int seg = blk & (SSEG - 1);
    int b = bh >> 3, hh = bh & 7;
    int tid = threadIdx.x;
    int q = tid & 7;
    int pl = tid >> 3;              // 0..31
    int q2 = q >> 1;
    __shared__ __align__(16) float sBC[2 * CT * 128];
    __shared__ __align__(16) float sX[CT][HP];
    __shared__ float sdt[CT], sdA[CT], srdA[CT];
    float h0[16], h1[16];
    #pragma unroll
    for (int i = 0; i < 16; i++) { h0[i] = 0.f; h1[i] = 0.f; }
    float Dh = Dvec[hh];
    float Ahv = -expf(Alog[hh]);
    float c_run = 1.f;
    const size_t base = (size_t)b * LSEQ + (size_t)seg * TSEG;
    int col = tid & 127, half = tid >> 7;
    int sw = swz8(col);
    int xc = tid & 63, xh = tid >> 6;

    float rB[8], rC[8], rX[4], rdt = 0.f;
    #pragma unroll
    for (int u = 0; u < 8; u++) {
        size_t m = base + 2 * u + half;
        rB[u] = Bm[m * D_STATE + col];
        rC[u] = Cm[m * D_STATE + col];
    }
    #pragma unroll
    for (int u = 0; u < 4; u++)
        rX[u] = xs[(base + 4 * u + xh) * D_INNER + hh * HP + xc];
    if (tid < CT) rdt = dtv[(base + tid) * NH + hh];

    for (int c0 = 0; c0 < TSEG; c0 += CT) {
        #pragma unroll
        for (int u = 0; u < 8; u++) {
            int s = 2 * u + half;
            sBC[s * 128 + sw] = rB[u];
            sBC[(CT + s) * 128 + sw] = rC[u];
        }
        #pragma unroll
        for (int u = 0; u < 4; u++)
            sX[4 * u + xh][xc] = rX[u];
        if (tid < CT) {
            float e = fmaxf(rdt * Ahv, -37.f);
            sdt[tid] = rdt;
            sdA[tid] = expf(e);
            srdA[tid] = expf(-e);
        }
        __syncthreads();
        if (c0 + CT < TSEG) {
            size_t nb = base + c0 + CT;
            #pragma unroll
            for (int u = 0; u < 8; u++) {
                size_t m = nb + 2 * u + half;
                rB[u] = Bm[m * D_STATE + col];
                rC[u] = Cm[m * D_STATE + col];
            }
            #pragma unroll
            for (int u = 0; u < 4; u++)
                rX[u] = xs[(nb + 4 * u + xh) * D_INNER + hh * HP + xc];
            if (tid < CT) rdt = dtv[(nb + tid) * NH + hh];
        }
        if (tid == 0) {
            float cg = c_run;
            for (int s = 0; s < CT; s++) {
                cg *= sdA[s];
                cumdA[(base + c0 + s) * NH + hh] = cg;
            }
            c_run = cg;
        }
        float cc = 1.f, rc = 1.f;
        #pragma unroll
        for (int s = 0; s < CT; s++) {
            float dAl = sdA[s], dtl = sdt[s];
            float ccn = cc * dAl;
            if (ccn < 1e-18f) {          // rare, wave-uniform rebase
                #pragma unroll
                for (int i = 0; i < 16; i++) { h0[i] *= cc; h1[i] *= cc; }
                rc = srdA[s];
                ccn = dAl;
            } else {
                rc *= srdA[s];
            }
            cc = ccn;
            float xv0 = sX[s][pl];
            float xv1 = sX[s][pl + 32];
            float dr = dtl * rc;
            float t0 = dr * xv0, t1 = dr * xv1;
            float ya0 = 0.f, yb0 = 0.f, ya1 = 0.f, yb1 = 0.f;
            #pragma unroll
            for (int i = 0; i < 4; i++) {
                int off = (q << 4) + (((i + q2) & 3) << 2);
                float4 bv = *(const float4*)&sBC[s * 128 + off];
                float4 cv = *(const float4*)&sBC[(CT + s) * 128 + off];
                h0[4*i+0] = fmaf(t0, bv.x, h0[4*i+0]); ya0 = fmaf(h0[4*i+0], cv.x, ya0);
                h0[4*i+1] = fmaf(t0, bv.y, h0[4*i+1]); yb0 = fmaf(h0[4*i+1], cv.y, yb0);
                h0[4*i+2] = fmaf(t0, bv.z, h0[4*i+2]); ya0 = fmaf(h0[4*i+2], cv.z, ya0);
                h0[4*i+3] = fmaf(t0, bv.w, h0[4*i+3]); yb0 = fmaf(h0[4*i+3], cv.w, yb0);
                h1[4*i+0] = fmaf(t1, bv.x, h1[4*i+0]); ya1 = fmaf(h1[4*i+0], cv.x, ya1);
                h1[4*i+1] = fmaf(t1, bv.y, h1[4*i+1]); yb1 = fmaf(h1[4*i+1], cv.y, yb1);
                h1[4*i+2] = fmaf(t1, bv.z, h1[4*i+2]); ya1 = fmaf(h1[4*i+2], cv.z, ya1);
                h1[4*i+3] = fmaf(t1, bv.w, h1[4*i+3]); yb1 = fmaf(h1[4*i+3], cv.w, yb1);
            }
            float yp0 = ya0 + yb0;
            float yp1 = ya1 + yb1;
            yp0 += __shfl_xor(yp0, 1);  yp1 += __shfl_xor(yp1, 1);
            yp0 += __shfl_xor(yp0, 2);  yp1 += __shfl_xor(yp1, 2);
            yp0 += __shfl_xor(yp0, 4);  yp1 += __shfl_xor(yp1, 4);
            if (q == 0) {
                size_t row = (base + c0 + s) * D_INNER + hh * HP;
                y[row + pl]      = fmaf(Dh, xv0, cc * yp0);
                y[row + pl + 32] = fmaf(Dh, xv1, cc * yp1);
            }
            if ((s & (RS - 1)) == RS - 1) {   // sub-chunk flush -> true state
                #pragma unroll
                for (int i = 0; i < 16; i++) { h0[i] *= cc; h1[i] *= cc; }
                cc = 1.f; rc = 1.f;
            }
        }
        __syncthreads();
    }
    if (seg < SSEG - 1) {
        float* F0 = F + (((size_t)bh * (SSEG - 1) + seg) * HP + pl) * D_STATE + (q << 4);
        float* F1 = F + (((size_t)bh * (SSEG - 1) + seg) * HP + pl + 32) * D_STATE + (q << 4);
        #pragma unroll
        for (int i = 0; i < 4; i++) {
            *(float4*)(F0 + 4 * i) = make_float4(h0[4*i], h0[4*i+1], h0[4*i+2], h0[4*i+3]);
            *(float4*)(F1 + 4 * i) = make_float4(h1[4*i], h1[4*i+1], h1[4*i+2], h1[4*i+3]);
        }
    }
}

// ---------------- Pass C (fused combine), 2p x 16n, staged-prefetch ----------------
__global__ __launch_bounds__(256, 4)
void k_seg_fix(const float* __restrict__ Cm, const float* __restrict__ cumdA,
               const float* __restrict__ F, float* __restrict__ y) {
    int blk = blockIdx.x;
    int bh = blk / (SSEG - 1);
    int seg = blk - bh * (SSEG - 1) + 1;
    int b = bh >> 3, hh = bh & 7;
    int tid = threadIdx.x;
    int q = tid & 7;
    int pl = tid >> 3;
    int q2 = q >> 1;
    float g0[16], g1[16];
    #pragma unroll
    for (int i = 0; i < 16; i++) { g0[i] = 0.f; g1[i] = 0.f; }
    for (int s = 0; s < seg; s++) {
        float P = cumdA[((size_t)b * LSEQ + (size_t)(s + 1) * TSEG - 1) * NH + hh];
        const float* F0 = F + (((size_t)bh * (SSEG - 1) + s) * HP + pl) * D_STATE + (q << 4);
        const float* F1 = F + (((size_t)bh * (SSEG - 1) + s) * HP + pl + 32) * D_STATE + (q << 4);
        #pragma unroll
        for (int i = 0; i < 4; i++) {
            float4 f0 = *(const float4*)(F0 + 4 * i);
            float4 f1 = *(const float4*)(F1 + 4 * i);
            g0[4*i+0] = fmaf(g0[4*i+0], P, f0.x);
            g0[4*i+1] = fmaf(g0[4*i+1], P, f0.y);
            g0[4*i+2] = fmaf(g0[4*i+2], P, f0.z);
            g0[4*i+3] = fmaf(g0[4*i+3], P, f0.w);
            g1[4*i+0] = fmaf(g1[4*i+0], P, f1.x);
            g1[4*i+1] = fmaf(g1[4*i+1], P, f1.y);
            g1[4*i+2] = fmaf(g1[4*i+2], P, f1.z);
            g1[4*i+3] = fmaf(g1[4*i+3], P, f1.w);
        }
    }
    __shared__ __align__(16) float sC[CT * 128];
    __shared__ float scd[CT];
    const size_t base = (size_t)b * LSEQ + (size_t)seg * TSEG;
    int col = tid & 127, half = tid >> 7;
    int sw = swz8(col);
    float rC[8], rcd = 0.f;
    #pragma unroll
    for (int u = 0; u < 8; u++)
        rC[u] = Cm[(base + 2 * u + half) * D_STATE + col];
    if (tid < CT) rcd = cumdA[(base + tid) * NH + hh];

    for (int c0 = 0; c0 < TSEG; c0 += CT) {
        #pragma unroll
        for (int u = 0; u < 8; u++)
            sC[(2 * u + half) * 128 + sw] = rC[u];
        if (tid < CT) scd[tid] = rcd;
        __syncthreads();
        if (c0 + CT < TSEG) {
            size_t nb = base + c0 + CT;
            #pragma unroll
            for (int u = 0; u < 8; u++)
                rC[u] = Cm[(nb + 2 * u + half) * D_STATE + col];
            if (tid < CT) rcd = cumdA[(nb + tid) * NH + hh];
        }
        #pragma unroll 1
        for (int s = 0; s < CT; s++) {
            float ya0 = 0.f, yb0 = 0.f, ya1 = 0.f, yb1 = 0.f;
            #pragma unroll
            for (int i = 0; i < 4; i++) {
                int off = (q << 4) + (((i + q2) & 3) << 2);
                float4 cv = *(const float4*)&sC[s * 128 + off];
                ya0 = fmaf(g0[4*i+0], cv.x, ya0);
                yb0 = fmaf(g0[4*i+1], cv.y, yb0);
                ya0 = fmaf(g0[4*i+2], cv.z, ya0);
                yb0 = fmaf(g0[4*i+3], cv.w, yb0);
                ya1 = fmaf(g1[4*i+0], cv.x, ya1);
                yb1 = fmaf(g1[4*i+1], cv.y, yb1);
                ya1 = fmaf(g1[4*i+2], cv.z, ya1);
                yb1 = fmaf(g1[4*i+3], cv.w, yb1);
            }
            float yp0 = ya0 + yb0;
            float yp1 = ya1 + yb1;
            yp0 += __shfl_xor(yp0, 1);  yp1 += __shfl_xor(yp1, 1);
            yp0 += __shfl_xor(yp0, 2);  yp1 += __shfl_xor(yp1, 2);
            yp0 += __shfl_xor(yp0, 4);  yp1 += __shfl_xor(yp1, 4);
            if (q == 0) {
                size_t row = (base + c0 + s) * D_INNER + hh * HP;
                y[row + pl]      += scd[s] * yp0;
                y[row + pl + 32] += scd[s] * yp1;
            }
        }
        __syncthreads();
    }
}

// ---------------- gated RMSNorm (in-place on y) ----------------
__global__ __launch_bounds__(256)
void k_gate(float* __restrict__ y, const float* __restrict__ zbuf,
            const float* __restrict__ nw) {
    int m = blockIdx.x, tid = threadIdx.x;
    __shared__ float sred[8];
    float g[2];
    #pragma unroll
    for (int j = 0; j < 2; j++) {
        int d = tid + j * 256;
        float z = zbuf[(size_t)m * D_INNER + d];
        g[j] = y[(size_t)m * D_INNER + d] * silu_f(z);
    }
    float2 s = block_reduce2(g[0] * g[0] + g[1] * g[1], 0.f, sred);
    float r = rsqrtf(s.x * (1.f / D_INNER) + EPS);
    #pragma unroll
    for (int j = 0; j < 2; j++) {
        int d = tid + j * 256;
        y[(size_t)m * D_INNER + d] = g[j] * r * nw[d];
    }
}

// ---------------- h = LN(mo + h) ----------------
__global__ __launch_bounds__(256)
void k_addln(const float* __restrict__ mo, float* __restrict__ h,
             const float* __restrict__ w, const float* __restrict__ bias) {
    int m = blockIdx.x, o = threadIdx.x;
    __shared__ float sred[8];
    float v = mo[(size_t)m * D_MODEL + o] + h[(size_t)m * D_MODEL + o];
    float2 s = block_reduce2(v, v * v, sred);
    float mu = s.x * (1.f / D_MODEL);
    float var = s.y * (1.f / D_MODEL) - mu * mu;
    h[(size_t)m * D_MODEL + o] = (v - mu) * rsqrtf(var + EPS) * w[o] + bias[o];
}

// ---------------- pooled partial sums: 16 chunks of 64 tokens per batch ----------
__global__ __launch_bounds__(256)
void k_pool_part(const float* __restrict__ h, const int* __restrict__ len,
                 float* __restrict__ part) {
    int blk = blockIdx.x;
    int b = blk >> 4, ch = blk & 15;
    int d = threadIdx.x;
    int Lb = len[b];
    int l0 = ch * 64;
    int le = min(l0 + 64, Lb);
    float acc = 0.f;
    for (int l = l0; l < le; l++) acc += h[((size_t)b * LSEQ + l) * D_MODEL + d];
    part[(size_t)blk * D_MODEL + d] = acc;
}

// ---------------- final head: pooled mean + 14-way linear ----------------
__global__ __launch_bounds__(256)
void k_head(const float* __restrict__ part, const int* __restrict__ len,
            const float* __restrict__ hw, const float* __restrict__ hb,
            float* __restrict__ out) {
    int b = blockIdx.x, d = threadIdx.x;
    __shared__ float sp[D_MODEL];
    float a = 0.f;
    #pragma unroll
    for (int c = 0; c < 16; c++) a += part[(size_t)(b * 16 + c) * D_MODEL + d];
    sp[d] = a / (float)len[b];
    __syncthreads();
    if (d < N_CLS) {
        float o = hb[d];
        const float* wr = hw + (size_t)d * D_MODEL;
        #pragma unroll 8
        for (int k = 0; k < D_MODEL; k++) o = fmaf(sp[k], wr[k], o);
        out[b * N_CLS + d] = o;
    }
}

extern "C" void kernel_launch(void* const* d_in, const int* in_sizes, int n_in,
                              void* d_out, int out_size, void* d_ws, size_t ws_size,
                              hipStream_t stream) {
    const float* x      = (const float*)d_in[0];
    const float* in_w   = (const float*)d_in[1];
    const float* in_b   = (const float*)d_in[2];
    const float* lnin_w = (const float*)d_in[3];
    const float* lnin_b = (const float*)d_in[4];
    const float* inproj = (const float*)d_in[5];
    const float* conv_w = (const float*)d_in[6];
    const float* conv_b = (const float*)d_in[7];
    const float* dt_bias= (const float*)d_in[8];
    const float* A_log  = (const float*)d_in[9];
    const float* Dv     = (const float*)d_in[10];
    const float* norm_w = (const float*)d_in[11];
    const float* outp_w = (const float*)d_in[12];
    const float* ln_w   = (const float*)d_in[13];
    const float* ln_b   = (const float*)d_in[14];
    const float* head_w = (const float*)d_in[15];
    const float* head_b = (const float*)d_in[16];
    const int*   lengths= (const int*)d_in[17];
    float* out = (float*)d_out;

    float* ws    = (float*)d_ws;
    float* h     = ws;
    float* buf1  = h    + (size_t)NTOK * D_MODEL;
    float* xs    = buf1 + (size_t)NTOK * XBCDT;
    float* Bm    = xs   + (size_t)NTOK * D_INNER;
    float* Cm    = Bm   + (size_t)NTOK * D_STATE;
    float* dtv   = Cm   + (size_t)NTOK * D_STATE;
    float* cumdA = dtv  + (size_t)NTOK * NH;
    float* zbuf  = buf1;
    float* F     = buf1 + (size_t)NTOK * D_INNER;
    float* mo    = Bm;
    float* xp    = buf1;
    float* pre   = buf1 + (size_t)NTOK * 64;
    float* poolp = buf1;
    unsigned short* WP = (unsigned short*)(ws + WS_BASE);
    bool use_pk = (ws_size >= WS_NEED);

    dim3 gIO(D_MODEL / 128, NTOK / 128);
    dim3 g1a((XBCDT + 127) / 128, NTOK / 128);
    dim3 g1b(D_INNER / 128, NTOK / 128);
    int gScan = BSZ * NH * SSEG;
    int gFix  = BSZ * NH * (SSEG - 1);

    if (use_pk) {
        k_pack_weights<<<TOTPK / 256, 256, 0, stream>>>(in_w, inproj, outp_w, WP);
        k_pack_x<<<NTOK * 64 / 256, 256, 0, stream>>>(x, xp);
        k_gemm_as<<<gIO, 256, 0, stream>>>(xp, WP + IN_HI, WP + IN_LO, pre,
                                           NTOK, D_MODEL, 64);
        k_lnio<<<NTOK, 256, 0, stream>>>(pre, in_b, lnin_w, lnin_b, h);
        for (int i = 0; i < NL; i++) {
            const u16* iph = WP + IP_HI + (size_t)i * PROJ * D_MODEL;
            const u16* ipl = WP + IP_LO + (size_t)i * PROJ * D_MODEL;
            k_gemm_as<<<g1a, 256, 0, stream>>>(h, iph + (size_t)D_INNER * D_MODEL,
                                               ipl + (size_t)D_INNER * D_MODEL,
                                               buf1, NTOK, XBCDT, D_MODEL);
            k_conv<<<NTOK, 256, 0, stream>>>(buf1, conv_w + i * DCONV * CONV_CH,
                                             conv_b + i * CONV_CH, dt_bias + i * NH,
                                             xs, Bm, Cm, dtv);
            k_gemm_as<<<g1b, 256, 0, stream>>>(h, iph, ipl, zbuf, NTOK, D_INNER, D_MODEL);
            k_scan_seg<<<gScan, 256, 0, stream>>>(xs, Bm, Cm, dtv,
                                                  A_log + i * NH, Dv + i * NH,
                                                  xs, F, cumdA);
            k_seg_fix<<<gFix, 256, 0, stream>>>(Cm, cumdA, F, xs);
            k_gate<<<NTOK, 256, 0, stream>>>(xs, zbuf, norm_w + i * D_INNER);
            k_gemm_as<<<gIO, 256, 0, stream>>>(xs, WP + OP_HI + (size_t)i * D_MODEL * D_INNER,
                                               WP + OP_LO + (size_t)i * D_MODEL * D_INNER,
                                               mo, NTOK, D_MODEL, D_INNER);
            k_addln<<<NTOK, 256, 0, stream>>>(mo, h, ln_w + i * D_MODEL, ln_b + i * D_MODEL);
        }
    } else {
        float* wp = Bm;
        k_pack_x<<<NTOK * 64 / 256, 256, 0, stream>>>(x, xp);
        k_pack_w<<<64, 256, 0, stream>>>(in_w, wp);
        k_gemm_mfma<<<gIO, 256, 0, stream>>>(xp, wp, pre, NTOK, D_MODEL, 64);
        k_lnio<<<NTOK, 256, 0, stream>>>(pre, in_b, lnin_w, lnin_b, h);
        for (int i = 0; i < NL; i++) {
            const float* W = inproj + (size_t)i * PROJ * D_MODEL;
            k_gemm_mfma<<<g1a, 256, 0, stream>>>(h, W + (size_t)D_INNER * D_MODEL,
                                                 buf1, NTOK, XBCDT, D_MODEL);
            k_conv<<<NTOK, 256, 0, stream>>>(buf1, conv_w + i * DCONV * CONV_CH,
                                             conv_b + i * CONV_CH, dt_bias + i * NH,
                                             xs, Bm, Cm, dtv);
            k_gemm_mfma<<<g1b, 256, 0, stream>>>(h, W, zbuf, NTOK, D_INNER, D_MODEL);
            k_scan_seg<<<gScan, 256, 0, stream>>>(xs, Bm, Cm, dtv,
                                                  A_log + i * NH, Dv + i * NH,
                                                  xs, F, cumdA);
            k_seg_fix<<<gFix, 256, 0, stream>>>(Cm, cumdA, F, xs);
            k_gate<<<NTOK, 256, 0, stream>>>(xs, zbuf, norm_w + i * D_INNER);
            k_gemm_mfma<<<gIO, 256, 0, stream>>>(xs, outp_w + (size_t)i * D_MODEL * D_INNER,
                                                 mo, NTOK, D_MODEL, D_INNER);
            k_addln<<<NTOK, 256, 0, stream>>>(mo, h, ln_w + i * D_MODEL, ln_b + i * D_MODEL);
        }
    }

    k_pool_part<<<BSZ * 16, 256, 0, stream>>>(h, lengths, poolp);
    k_head<<<BSZ, 256, 0, stream>>>(poolp, lengths, head_w, head_b, out);
}